// Round 8
// baseline (204.819 us; speedup 1.0000x reference)
//
#include <hip/hip_runtime.h>
#include <hip/hip_bf16.h>
#include <hip/hip_fp16.h>

#define D_IN   128
#define D_OUT  64

#define CB_NODES  1024     // nodes per coarse bucket
#define NB1       98       // ceil(100000/1024)
#define CAP1      20480    // coarse region slots (mean ~16327, +32 sigma)
#define CHUNK1    2048     // edges per bin1 block (1024 thr x 2)

// ---------------------------------------------------------------------------
// W prep: wT[k][c] = W[c][k]  (8192 floats)
// ---------------------------------------------------------------------------
__global__ __launch_bounds__(256) void wprep_kernel(
    const float* __restrict__ Ww, float* __restrict__ wT)
{
    const int i = blockIdx.x * 256 + threadIdx.x;
    if (i < D_IN * D_OUT) {
        const int k = i >> 6;
        const int c = i & 63;
        wT[i] = Ww[c * D_IN + k];
    }
}

// ---------------------------------------------------------------------------
// Projection: lane-per-row, scalar-pipe weights (lane-invariant addresses).
// ---------------------------------------------------------------------------
__global__ __launch_bounds__(256, 4) void proj_kernel(
    const float* __restrict__ h, const float* __restrict__ wT,
    const float* __restrict__ Wb, const float* __restrict__ a,
    float* __restrict__ data, float* __restrict__ s_out, float* __restrict__ t_out,
    int n)
{
    const int row = blockIdx.x * 256 + threadIdx.x;
    if (row >= n) return;

    const float4* __restrict__ hrow = (const float4*)(h + (size_t)row * D_IN);

    float acc[D_OUT];
    #pragma unroll
    for (int c = 0; c < D_OUT; ++c) acc[c] = Wb[c];

    #pragma unroll 1
    for (int ch = 0; ch < 4; ++ch) {
        float4 hq[8];
        #pragma unroll
        for (int q = 0; q < 8; ++q) hq[q] = hrow[ch * 8 + q];

        #pragma unroll
        for (int q = 0; q < 8; ++q) {
            const float hv0 = hq[q].x, hv1 = hq[q].y, hv2 = hq[q].z, hv3 = hq[q].w;
            const int k0 = ch * 32 + q * 4;
            const float* __restrict__ w0 = wT + (size_t)(k0 + 0) * D_OUT;
            const float* __restrict__ w1 = wT + (size_t)(k0 + 1) * D_OUT;
            const float* __restrict__ w2 = wT + (size_t)(k0 + 2) * D_OUT;
            const float* __restrict__ w3 = wT + (size_t)(k0 + 3) * D_OUT;
            #pragma unroll
            for (int c = 0; c < D_OUT; ++c)
                acc[c] = fmaf(hv3, w3[c],
                         fmaf(hv2, w2[c],
                         fmaf(hv1, w1[c],
                         fmaf(hv0, w0[c], acc[c]))));
        }
    }

    float sp = 0.f, tp = 0.f;
    #pragma unroll
    for (int c = 0; c < D_OUT; ++c) {
        sp = fmaf(acc[c], a[c], sp);
        tp = fmaf(acc[c], a[D_OUT + c], tp);
    }
    s_out[row] = sp;
    t_out[row] = tp;

    float4* __restrict__ drow = (float4*)(data + (size_t)row * D_OUT);
    #pragma unroll
    for (int q = 0; q < 16; ++q)
        drow[q] = make_float4(acc[4*q], acc[4*q+1], acc[4*q+2], acc[4*q+3]);
}

// ---------------------------------------------------------------------------
// bin1: edges -> 98 coarse buckets. Record = (u_local10 << 17) | e1.
// ---------------------------------------------------------------------------
__global__ __launch_bounds__(1024) void bin1_kernel(
    const int* __restrict__ e0a, const int* __restrict__ e1a,
    int* __restrict__ cursor1, unsigned int* __restrict__ region1, int ne)
{
    __shared__ int cnt[128];
    __shared__ int basev[128];

    const int tid  = threadIdx.x;
    const int base = blockIdx.x * CHUNK1;

    if (tid < 128) cnt[tid] = 0;
    __syncthreads();

    int bj[2]; unsigned rc[2];
    #pragma unroll
    for (int j = 0; j < 2; ++j) {
        const int i = base + j * 1024 + tid;
        if (i < ne) {
            const int u = e0a[i];
            const int v = e1a[i];
            bj[j] = u >> 10;
            rc[j] = ((unsigned)(u & (CB_NODES - 1)) << 17) | (unsigned)v;
            atomicAdd(&cnt[bj[j]], 1);
        } else bj[j] = -1;
    }
    __syncthreads();

    if (tid < 128) {
        const int c = cnt[tid];
        basev[tid] = (c > 0) ? atomicAdd(&cursor1[tid], c) : 0;
        cnt[tid] = 0;
    }
    __syncthreads();

    #pragma unroll
    for (int j = 0; j < 2; ++j) {
        if (bj[j] >= 0) {
            const int p = basev[bj[j]] + atomicAdd(&cnt[bj[j]], 1);
            if (p < CAP1) region1[(size_t)bj[j] * CAP1 + p] = rc[j];
        }
    }
}

// ---------------------------------------------------------------------------
// bbase: exclusive scan of min(cursor1[b], CAP1) over 98 buckets (1 block).
// ---------------------------------------------------------------------------
__global__ __launch_bounds__(128) void bbase_kernel(
    const int* __restrict__ cursor1, int* __restrict__ bbase)
{
    __shared__ int wtot;
    const int tid  = threadIdx.x;
    const int lane = tid & 63;
    const int wv   = tid >> 6;
    const int v = (tid < NB1) ? min(cursor1[tid], CAP1) : 0;
    int x = v;
    #pragma unroll
    for (int off = 1; off < 64; off <<= 1) {
        int y = __shfl_up(x, off);
        if (lane >= off) x += y;
    }
    if (wv == 0 && lane == 63) wtot = x;
    __syncthreads();
    const int add = (wv == 1) ? wtot : 0;
    if (tid < NB1) bbase[tid] = add + x - v;
}

// ---------------------------------------------------------------------------
// Per-bucket CSR + edge weights: one 1024-thread block per bucket.
// LDS histogram + scan; computes w = exp(leakyrelu(s[u]+t[v])/8) per edge
// (once per edge, not per lane), writes se1 + fp16 wgt, accumulates wsum
// in LDS and writes winv (1/wsum) per node.
// ---------------------------------------------------------------------------
__global__ __launch_bounds__(1024) void bucket_csr_kernel(
    const int* __restrict__ cursor1, const unsigned int* __restrict__ region1,
    const int* __restrict__ bbase,
    const float* __restrict__ s, const float* __restrict__ t,
    int* __restrict__ counts, int* __restrict__ offs,
    float* __restrict__ winv,
    int* __restrict__ se1, __half* __restrict__ wgt, int n)
{
    __shared__ int   lcnt[CB_NODES];
    __shared__ int   loff[CB_NODES];
    __shared__ float wacc[CB_NODES];
    __shared__ float s_lds[CB_NODES];
    __shared__ int   wsum[16];

    const int b   = blockIdx.x;
    const int tid = threadIdx.x;
    const int cnt1 = min(cursor1[b], CAP1);
    const unsigned int* __restrict__ reg = region1 + (size_t)b * CAP1;
    const int u0 = b << 10;

    lcnt[tid] = 0;
    wacc[tid] = 0.f;
    {
        const int u = u0 + tid;
        s_lds[tid] = (u < n) ? s[u] : 0.f;
    }
    __syncthreads();

    for (int i = tid; i < cnt1; i += 1024)
        atomicAdd(&lcnt[reg[i] >> 17], 1);
    __syncthreads();

    // block-wide exclusive scan of lcnt[1024]
    const int lane = tid & 63;
    const int wv   = tid >> 6;
    const int deg = lcnt[tid];
    int x = deg;
    #pragma unroll
    for (int off = 1; off < 64; off <<= 1) {
        int y = __shfl_up(x, off);
        if (lane >= off) x += y;
    }
    if (lane == 63) wsum[wv] = x;
    __syncthreads();
    if (wv == 0) {
        const int wval = (lane < 16) ? wsum[lane] : 0;
        int wx = wval;
        #pragma unroll
        for (int off = 1; off < 16; off <<= 1) {
            int y = __shfl_up(wx, off);
            if (lane >= off) wx += y;
        }
        if (lane < 16) wsum[lane] = wx - wval;   // exclusive wave offsets
    }
    __syncthreads();
    const int excl = wsum[wv] + x - deg;

    const int base = bbase[b];
    loff[tid] = excl;
    lcnt[tid] = 0;
    __syncthreads();

    for (int i = tid; i < cnt1; i += 1024) {
        const unsigned r = reg[i];
        const int ul = (int)(r >> 17);
        const int v  = (int)(r & 0x1FFFFu);
        const float raw = s_lds[ul] + t[v];
        const float lr  = raw > 0.f ? raw : 0.2f * raw;
        const __half wh = __float2half(__expf(lr * 0.125f));
        const float  wf = __half2float(wh);       // rounded value, matches node
        atomicAdd(&wacc[ul], wf);
        const int p = base + loff[ul] + atomicAdd(&lcnt[ul], 1);
        se1[p] = v;
        wgt[p] = wh;
    }
    __syncthreads();

    const int u = u0 + tid;
    if (u < n) {
        counts[u] = deg;
        offs[u]   = base + excl;
        winv[u]   = (deg > 0) ? 1.0f / wacc[tid] : 0.f;
    }
}

// ---------------------------------------------------------------------------
// Node aggregation: one wave per node, lane = feature, unroll-4 gathers.
// Weights precomputed; epilogue multiplies by winv.
// ---------------------------------------------------------------------------
__global__ __launch_bounds__(256) void node_kernel(
    const int* __restrict__ se1, const __half* __restrict__ wgt,
    const int* __restrict__ offs, const int* __restrict__ counts,
    const float* __restrict__ winv,
    const float* __restrict__ data, float* __restrict__ out, int n)
{
    const int wave = threadIdx.x >> 6;
    const int lane = threadIdx.x & 63;
    const int u = blockIdx.x * 4 + wave;
    if (u >= n) return;

    const int start = offs[u];
    const int deg   = counts[u];

    float acc = 0.0f;

    int j = 0;
    for (; j + 4 <= deg; j += 4) {
        const int v0 = se1[start + j + 0];
        const int v1 = se1[start + j + 1];
        const int v2 = se1[start + j + 2];
        const int v3 = se1[start + j + 3];
        const float w0 = __half2float(wgt[start + j + 0]);
        const float w1 = __half2float(wgt[start + j + 1]);
        const float w2 = __half2float(wgt[start + j + 2]);
        const float w3 = __half2float(wgt[start + j + 3]);
        const float d0 = data[(size_t)v0 * D_OUT + lane];
        const float d1 = data[(size_t)v1 * D_OUT + lane];
        const float d2 = data[(size_t)v2 * D_OUT + lane];
        const float d3 = data[(size_t)v3 * D_OUT + lane];

        acc = fmaf(w0, d0, acc);
        acc = fmaf(w1, d1, acc);
        acc = fmaf(w2, d2, acc);
        acc = fmaf(w3, d3, acc);
    }
    for (; j < deg; ++j) {
        const int v0 = se1[start + j];
        const float w0 = __half2float(wgt[start + j]);
        const float d0 = data[(size_t)v0 * D_OUT + lane];
        acc = fmaf(w0, d0, acc);
    }

    float o;
    if (deg == 0) o = data[(size_t)u * D_OUT + lane];
    else          o = acc * winv[u];
    out[(size_t)u * D_OUT + lane] = o;
}

extern "C" void kernel_launch(void* const* d_in, const int* in_sizes, int n_in,
                              void* d_out, int out_size, void* d_ws, size_t ws_size,
                              hipStream_t stream)
{
    const float* h    = (const float*)d_in[0];
    const int*   edge = (const int*)d_in[1];
    const float* Ww   = (const float*)d_in[2];
    const float* Wb   = (const float*)d_in[3];
    const float* a    = (const float*)d_in[4];

    const int n  = in_sizes[0] / D_IN;    // 100000
    const int ne = in_sizes[1] / 2;       // 1600000

    const int* e0a = edge;
    const int* e1a = edge + ne;
    float* out = (float*)d_out;

    char* wsp = (char*)d_ws;
    float* data    = (float*)wsp;  wsp += (size_t)n * D_OUT * sizeof(float);
    float* s       = (float*)wsp;  wsp += (size_t)n * sizeof(float);
    float* t       = (float*)wsp;  wsp += (size_t)n * sizeof(float);
    int*   counts  = (int*)wsp;    wsp += (size_t)n * sizeof(int);
    int*   offs    = (int*)wsp;    wsp += (size_t)n * sizeof(int);
    float* winv    = (float*)wsp;  wsp += (size_t)n * sizeof(float);
    int*   cursor1 = (int*)wsp;    wsp += 128 * sizeof(int);
    int*   bbase   = (int*)wsp;    wsp += 128 * sizeof(int);
    float* wT      = (float*)wsp;  wsp += (size_t)D_IN * D_OUT * sizeof(float);
    unsigned int* region1 = (unsigned int*)wsp; wsp += (size_t)NB1 * CAP1 * sizeof(unsigned int);
    int*    se1    = (int*)wsp;    wsp += (size_t)ne * sizeof(int);
    __half* wgt    = (__half*)wsp; wsp += (size_t)ne * sizeof(__half);

    hipMemsetAsync(cursor1, 0, 128 * sizeof(int), stream);

    wprep_kernel<<<(D_IN * D_OUT + 255) / 256, 256, 0, stream>>>(Ww, wT);

    proj_kernel<<<(n + 255) / 256, 256, 0, stream>>>(
        h, wT, Wb, a, data, s, t, n);

    bin1_kernel<<<(ne + CHUNK1 - 1) / CHUNK1, 1024, 0, stream>>>(
        e0a, e1a, cursor1, region1, ne);

    bbase_kernel<<<1, 128, 0, stream>>>(cursor1, bbase);

    bucket_csr_kernel<<<NB1, 1024, 0, stream>>>(
        cursor1, region1, bbase, s, t, counts, offs, winv, se1, wgt, n);

    node_kernel<<<(n + 3) / 4, 256, 0, stream>>>(
        se1, wgt, offs, counts, winv, data, out, n);
}

// Round 9
// 202.180 us; speedup vs baseline: 1.0131x; 1.0131x over previous
//
#include <hip/hip_runtime.h>
#include <hip/hip_bf16.h>
#include <hip/hip_fp16.h>

#define D_IN   128
#define D_OUT  64

#define CB_NODES  1024     // nodes per coarse bucket (bin1 write locality)
#define SB_NODES  256      // nodes per sub-bucket (csr/scatter parallelism)
#define NB1       98       // ceil(100000/1024)
#define NSB       392      // NB1 * 4
#define CAP1      20480    // coarse region slots (mean ~16327, +32 sigma)
#define CHUNK1    2048     // edges per bin1 block (1024 thr x 2)

static __device__ __forceinline__ unsigned pack_h2(float a, float b) {
    __half2 h = __floats2half2_rn(a, b);
    return *reinterpret_cast<unsigned*>(&h);
}

// ---------------------------------------------------------------------------
// W prep: wT[k][c] = W[c][k]
// ---------------------------------------------------------------------------
__global__ __launch_bounds__(256) void wprep_kernel(
    const float* __restrict__ Ww, float* __restrict__ wT)
{
    const int i = blockIdx.x * 256 + threadIdx.x;
    if (i < D_IN * D_OUT) {
        const int k = i >> 6;
        const int c = i & 63;
        wT[i] = Ww[c * D_IN + k];
    }
}

// ---------------------------------------------------------------------------
// Projection: lane-per-row, scalar-pipe weights. Writes fp16 data16.
// ---------------------------------------------------------------------------
__global__ __launch_bounds__(256, 4) void proj_kernel(
    const float* __restrict__ h, const float* __restrict__ wT,
    const float* __restrict__ Wb, const float* __restrict__ a,
    unsigned* __restrict__ data16, float* __restrict__ s_out, float* __restrict__ t_out,
    int n)
{
    const int row = blockIdx.x * 256 + threadIdx.x;
    if (row >= n) return;

    const float4* __restrict__ hrow = (const float4*)(h + (size_t)row * D_IN);

    float acc[D_OUT];
    #pragma unroll
    for (int c = 0; c < D_OUT; ++c) acc[c] = Wb[c];

    #pragma unroll 1
    for (int ch = 0; ch < 4; ++ch) {
        float4 hq[8];
        #pragma unroll
        for (int q = 0; q < 8; ++q) hq[q] = hrow[ch * 8 + q];

        #pragma unroll
        for (int q = 0; q < 8; ++q) {
            const float hv0 = hq[q].x, hv1 = hq[q].y, hv2 = hq[q].z, hv3 = hq[q].w;
            const int k0 = ch * 32 + q * 4;
            const float* __restrict__ w0 = wT + (size_t)(k0 + 0) * D_OUT;
            const float* __restrict__ w1 = wT + (size_t)(k0 + 1) * D_OUT;
            const float* __restrict__ w2 = wT + (size_t)(k0 + 2) * D_OUT;
            const float* __restrict__ w3 = wT + (size_t)(k0 + 3) * D_OUT;
            #pragma unroll
            for (int c = 0; c < D_OUT; ++c)
                acc[c] = fmaf(hv3, w3[c],
                         fmaf(hv2, w2[c],
                         fmaf(hv1, w1[c],
                         fmaf(hv0, w0[c], acc[c]))));
        }
    }

    float sp = 0.f, tp = 0.f;
    #pragma unroll
    for (int c = 0; c < D_OUT; ++c) {
        sp = fmaf(acc[c], a[c], sp);
        tp = fmaf(acc[c], a[D_OUT + c], tp);
    }
    s_out[row] = sp;
    t_out[row] = tp;

    uint4* __restrict__ drow = (uint4*)(data16 + (size_t)row * 32);
    #pragma unroll
    for (int g = 0; g < 8; ++g) {
        uint4 pk;
        pk.x = pack_h2(acc[8*g+0], acc[8*g+1]);
        pk.y = pack_h2(acc[8*g+2], acc[8*g+3]);
        pk.z = pack_h2(acc[8*g+4], acc[8*g+5]);
        pk.w = pack_h2(acc[8*g+6], acc[8*g+7]);
        drow[g] = pk;
    }
}

// ---------------------------------------------------------------------------
// bin1: edges -> 98 coarse regions (write-local) + global sub-bucket counts.
// Record = (u_local10 << 17) | e1
// ---------------------------------------------------------------------------
__global__ __launch_bounds__(1024) void bin1_kernel(
    const int* __restrict__ e0a, const int* __restrict__ e1a,
    int* __restrict__ cursor1, int* __restrict__ subcnt,
    unsigned int* __restrict__ region1, int ne)
{
    __shared__ int cnt[128];
    __shared__ int basev[128];
    __shared__ int scnt[NSB];

    const int tid  = threadIdx.x;
    const int base = blockIdx.x * CHUNK1;

    if (tid < 128) cnt[tid] = 0;
    if (tid < NSB) scnt[tid] = 0;
    __syncthreads();

    int bj[2]; unsigned rc[2];
    #pragma unroll
    for (int j = 0; j < 2; ++j) {
        const int i = base + j * 1024 + tid;
        if (i < ne) {
            const int u = e0a[i];
            const int v = e1a[i];
            bj[j] = u >> 10;
            rc[j] = ((unsigned)(u & (CB_NODES - 1)) << 17) | (unsigned)v;
            atomicAdd(&cnt[bj[j]], 1);
            atomicAdd(&scnt[u >> 8], 1);
        } else bj[j] = -1;
    }
    __syncthreads();

    if (tid < 128) {
        const int c = cnt[tid];
        basev[tid] = (c > 0) ? atomicAdd(&cursor1[tid], c) : 0;
        cnt[tid] = 0;
    }
    if (tid < NSB) {
        const int c = scnt[tid];
        if (c > 0) atomicAdd(&subcnt[tid], c);
    }
    __syncthreads();

    #pragma unroll
    for (int j = 0; j < 2; ++j) {
        if (bj[j] >= 0) {
            const int p = basev[bj[j]] + atomicAdd(&cnt[bj[j]], 1);
            if (p < CAP1) region1[(size_t)bj[j] * CAP1 + p] = rc[j];
        }
    }
}

// ---------------------------------------------------------------------------
// sbase: exclusive scan of subcnt[392] (one 512-thread block).
// ---------------------------------------------------------------------------
__global__ __launch_bounds__(512) void sbase_kernel(
    const int* __restrict__ subcnt, int* __restrict__ sbase)
{
    __shared__ int wsum[8];
    const int tid  = threadIdx.x;
    const int lane = tid & 63;
    const int wv   = tid >> 6;
    const int v = (tid < NSB) ? subcnt[tid] : 0;
    int x = v;
    #pragma unroll
    for (int off = 1; off < 64; off <<= 1) {
        int y = __shfl_up(x, off);
        if (lane >= off) x += y;
    }
    if (lane == 63) wsum[wv] = x;
    __syncthreads();
    if (wv == 0) {
        const int wval = (lane < 8) ? wsum[lane] : 0;
        int wx = wval;
        #pragma unroll
        for (int off = 1; off < 8; off <<= 1) {
            int y = __shfl_up(wx, off);
            if (lane >= off) wx += y;
        }
        if (lane < 8) wsum[lane] = wx - wval;
    }
    __syncthreads();
    if (tid < NSB) sbase[tid] = wsum[wv] + x - v;
}

// ---------------------------------------------------------------------------
// csr: one 256-thread block per sub-bucket (392 blocks). Filters its coarse
// region, builds per-node CSR, computes fp16 edge weights + winv.
// ---------------------------------------------------------------------------
__global__ __launch_bounds__(256) void csr_kernel(
    const int* __restrict__ cursor1, const unsigned int* __restrict__ region1,
    const int* __restrict__ sbase,
    const float* __restrict__ s, const float* __restrict__ t,
    int* __restrict__ counts, int* __restrict__ offs,
    float* __restrict__ winv,
    int* __restrict__ se1, __half* __restrict__ wgt, int n)
{
    __shared__ int   lcnt[SB_NODES];
    __shared__ int   loff[SB_NODES];
    __shared__ float wacc[SB_NODES];
    __shared__ float s_lds[SB_NODES];
    __shared__ int   wsum[4];

    const int sb  = blockIdx.x;
    const int b   = sb >> 2;
    const unsigned q = (unsigned)(sb & 3);
    const int tid = threadIdx.x;
    const int u0  = sb << 8;

    const int cnt1 = min(cursor1[b], CAP1);
    const unsigned int* __restrict__ reg = region1 + (size_t)b * CAP1;

    lcnt[tid] = 0;
    wacc[tid] = 0.f;
    {
        const int u = u0 + tid;
        s_lds[tid] = (u < n) ? s[u] : 0.f;
    }
    __syncthreads();

    // pass 1: histogram (filter: top 2 bits of ul10 == q)
    for (int i = tid; i < cnt1; i += 256) {
        const unsigned r = reg[i];
        if ((r >> 25) == q)
            atomicAdd(&lcnt[(r >> 17) & (SB_NODES - 1)], 1);
    }
    __syncthreads();

    // block-wide exclusive scan of lcnt[256]
    const int lane = tid & 63;
    const int wv   = tid >> 6;
    const int deg  = lcnt[tid];
    int x = deg;
    #pragma unroll
    for (int off = 1; off < 64; off <<= 1) {
        int y = __shfl_up(x, off);
        if (lane >= off) x += y;
    }
    if (lane == 63) wsum[wv] = x;
    __syncthreads();
    if (wv == 0) {
        const int wval = (lane < 4) ? wsum[lane] : 0;
        int wx = wval;
        #pragma unroll
        for (int off = 1; off < 4; off <<= 1) {
            int y = __shfl_up(wx, off);
            if (lane >= off) wx += y;
        }
        if (lane < 4) wsum[lane] = wx - wval;
    }
    __syncthreads();
    const int excl = wsum[wv] + x - deg;
    const int base = sbase[sb];

    loff[tid] = excl;
    lcnt[tid] = 0;
    __syncthreads();

    // pass 2: scatter + weight
    for (int i = tid; i < cnt1; i += 256) {
        const unsigned r = reg[i];
        if ((r >> 25) != q) continue;
        const int ul = (int)((r >> 17) & (SB_NODES - 1));
        const int v  = (int)(r & 0x1FFFFu);
        const float raw = s_lds[ul] + t[v];
        const float lr  = raw > 0.f ? raw : 0.2f * raw;
        const __half wh = __float2half(__expf(lr * 0.125f));
        atomicAdd(&wacc[ul], __half2float(wh));
        const int p = base + loff[ul] + atomicAdd(&lcnt[ul], 1);
        se1[p] = v;
        wgt[p] = wh;
    }
    __syncthreads();

    const int u = u0 + tid;
    if (u < n) {
        counts[u] = deg;
        offs[u]   = base + excl;
        winv[u]   = (deg > 0) ? 1.0f / wacc[tid] : 0.f;
    }
}

// ---------------------------------------------------------------------------
// Node aggregation: wave per node; lanes 0-31 = even edge, 32-63 = odd edge;
// each lane holds a half2 feature pair. fp16 data gather (128 B/edge-row).
// ---------------------------------------------------------------------------
__global__ __launch_bounds__(256) void node_kernel(
    const int* __restrict__ se1, const __half* __restrict__ wgt,
    const int* __restrict__ offs, const int* __restrict__ counts,
    const float* __restrict__ winv,
    const __half2* __restrict__ data16, float* __restrict__ out, int n)
{
    const int wave = threadIdx.x >> 6;
    const int lane = threadIdx.x & 63;
    const int half = lane >> 5;
    const int c2   = lane & 31;
    const int u = blockIdx.x * 4 + wave;
    if (u >= n) return;

    const int start = offs[u];
    const int deg   = counts[u];

    float ax = 0.f, ay = 0.f;

    int j = 0;
    for (; j + 8 <= deg; j += 8) {
        const int e0 = start + j + half;
        const int v0 = se1[e0];
        const int v1 = se1[e0 + 2];
        const int v2 = se1[e0 + 4];
        const int v3 = se1[e0 + 6];
        const float w0 = __half2float(wgt[e0]);
        const float w1 = __half2float(wgt[e0 + 2]);
        const float w2 = __half2float(wgt[e0 + 4]);
        const float w3 = __half2float(wgt[e0 + 6]);
        const float2 f0 = __half22float2(data16[(size_t)v0 * 32 + c2]);
        const float2 f1 = __half22float2(data16[(size_t)v1 * 32 + c2]);
        const float2 f2 = __half22float2(data16[(size_t)v2 * 32 + c2]);
        const float2 f3 = __half22float2(data16[(size_t)v3 * 32 + c2]);
        ax = fmaf(w0, f0.x, ax); ay = fmaf(w0, f0.y, ay);
        ax = fmaf(w1, f1.x, ax); ay = fmaf(w1, f1.y, ay);
        ax = fmaf(w2, f2.x, ax); ay = fmaf(w2, f2.y, ay);
        ax = fmaf(w3, f3.x, ax); ay = fmaf(w3, f3.y, ay);
    }
    for (; j < deg; j += 2) {
        if (j + half < deg) {
            const int e = start + j + half;
            const int v = se1[e];
            const float w = __half2float(wgt[e]);
            const float2 f = __half22float2(data16[(size_t)v * 32 + c2]);
            ax = fmaf(w, f.x, ax); ay = fmaf(w, f.y, ay);
        }
    }

    ax += __shfl_xor(ax, 32);
    ay += __shfl_xor(ay, 32);

    if (half == 0) {
        float2 o;
        if (deg == 0) {
            o = __half22float2(data16[(size_t)u * 32 + c2]);
        } else {
            const float wi = winv[u];
            o = make_float2(ax * wi, ay * wi);
        }
        ((float2*)out)[(size_t)u * 32 + c2] = o;
    }
}

extern "C" void kernel_launch(void* const* d_in, const int* in_sizes, int n_in,
                              void* d_out, int out_size, void* d_ws, size_t ws_size,
                              hipStream_t stream)
{
    const float* h    = (const float*)d_in[0];
    const int*   edge = (const int*)d_in[1];
    const float* Ww   = (const float*)d_in[2];
    const float* Wb   = (const float*)d_in[3];
    const float* a    = (const float*)d_in[4];

    const int n  = in_sizes[0] / D_IN;    // 100000
    const int ne = in_sizes[1] / 2;       // 1600000

    const int* e0a = edge;
    const int* e1a = edge + ne;
    float* out = (float*)d_out;

    char* wsp = (char*)d_ws;
    unsigned* data16 = (unsigned*)wsp; wsp += (size_t)n * 32 * sizeof(unsigned); // 64 fp16/row
    float* s       = (float*)wsp;  wsp += (size_t)n * sizeof(float);
    float* t       = (float*)wsp;  wsp += (size_t)n * sizeof(float);
    int*   counts  = (int*)wsp;    wsp += (size_t)n * sizeof(int);
    int*   offs    = (int*)wsp;    wsp += (size_t)n * sizeof(int);
    float* winv    = (float*)wsp;  wsp += (size_t)n * sizeof(float);
    int*   cursor1 = (int*)wsp;    wsp += 128 * sizeof(int);
    int*   subcnt  = (int*)wsp;    wsp += 512 * sizeof(int);
    int*   sbase   = (int*)wsp;    wsp += 512 * sizeof(int);
    float* wT      = (float*)wsp;  wsp += (size_t)D_IN * D_OUT * sizeof(float);
    unsigned int* region1 = (unsigned int*)wsp; wsp += (size_t)NB1 * CAP1 * sizeof(unsigned int);
    int*    se1    = (int*)wsp;    wsp += (size_t)ne * sizeof(int);
    __half* wgt    = (__half*)wsp; wsp += (size_t)ne * sizeof(__half);

    hipMemsetAsync(cursor1, 0, (128 + 512) * sizeof(int), stream);

    wprep_kernel<<<(D_IN * D_OUT + 255) / 256, 256, 0, stream>>>(Ww, wT);

    proj_kernel<<<(n + 255) / 256, 256, 0, stream>>>(
        h, wT, Wb, a, data16, s, t, n);

    bin1_kernel<<<(ne + CHUNK1 - 1) / CHUNK1, 1024, 0, stream>>>(
        e0a, e1a, cursor1, subcnt, region1, ne);

    sbase_kernel<<<1, 512, 0, stream>>>(subcnt, sbase);

    csr_kernel<<<NSB, 256, 0, stream>>>(
        cursor1, region1, sbase, s, t, counts, offs, winv, se1, wgt, n);

    node_kernel<<<(n + 3) / 4, 256, 0, stream>>>(
        se1, wgt, offs, counts, winv, (const __half2*)data16, out, n);
}

// Round 10
// 192.942 us; speedup vs baseline: 1.0616x; 1.0479x over previous
//
#include <hip/hip_runtime.h>
#include <hip/hip_bf16.h>
#include <hip/hip_fp16.h>

#define D_IN   128
#define D_OUT  64

#define CB_NODES  1024     // nodes per coarse bucket (bin1 write locality)
#define SB_NODES  64       // nodes per sub-bucket (csr parallelism)
#define NB1       98       // ceil(100000/1024)
#define NSB       1568     // NB1 * 16
#define CAP1      20480    // coarse region slots (mean ~16327, +32 sigma)
#define CHUNK1    2048     // edges per bin1 block (1024 thr x 2)

static __device__ __forceinline__ unsigned pack_h2(float a, float b) {
    __half2 h = __floats2half2_rn(a, b);
    return *reinterpret_cast<unsigned*>(&h);
}

// ---------------------------------------------------------------------------
// W prep: wT[k][c] = W[c][k]
// ---------------------------------------------------------------------------
__global__ __launch_bounds__(256) void wprep_kernel(
    const float* __restrict__ Ww, float* __restrict__ wT)
{
    const int i = blockIdx.x * 256 + threadIdx.x;
    if (i < D_IN * D_OUT) {
        const int k = i >> 6;
        const int c = i & 63;
        wT[i] = Ww[c * D_IN + k];
    }
}

// ---------------------------------------------------------------------------
// Projection: lane-per-row, scalar-pipe weights. Writes fp16 data16.
// ---------------------------------------------------------------------------
__global__ __launch_bounds__(256, 4) void proj_kernel(
    const float* __restrict__ h, const float* __restrict__ wT,
    const float* __restrict__ Wb, const float* __restrict__ a,
    unsigned* __restrict__ data16, float* __restrict__ s_out, float* __restrict__ t_out,
    int n)
{
    const int row = blockIdx.x * 256 + threadIdx.x;
    if (row >= n) return;

    const float4* __restrict__ hrow = (const float4*)(h + (size_t)row * D_IN);

    float acc[D_OUT];
    #pragma unroll
    for (int c = 0; c < D_OUT; ++c) acc[c] = Wb[c];

    #pragma unroll 1
    for (int ch = 0; ch < 4; ++ch) {
        float4 hq[8];
        #pragma unroll
        for (int q = 0; q < 8; ++q) hq[q] = hrow[ch * 8 + q];

        #pragma unroll
        for (int q = 0; q < 8; ++q) {
            const float hv0 = hq[q].x, hv1 = hq[q].y, hv2 = hq[q].z, hv3 = hq[q].w;
            const int k0 = ch * 32 + q * 4;
            const float* __restrict__ w0 = wT + (size_t)(k0 + 0) * D_OUT;
            const float* __restrict__ w1 = wT + (size_t)(k0 + 1) * D_OUT;
            const float* __restrict__ w2 = wT + (size_t)(k0 + 2) * D_OUT;
            const float* __restrict__ w3 = wT + (size_t)(k0 + 3) * D_OUT;
            #pragma unroll
            for (int c = 0; c < D_OUT; ++c)
                acc[c] = fmaf(hv3, w3[c],
                         fmaf(hv2, w2[c],
                         fmaf(hv1, w1[c],
                         fmaf(hv0, w0[c], acc[c]))));
        }
    }

    float sp = 0.f, tp = 0.f;
    #pragma unroll
    for (int c = 0; c < D_OUT; ++c) {
        sp = fmaf(acc[c], a[c], sp);
        tp = fmaf(acc[c], a[D_OUT + c], tp);
    }
    s_out[row] = sp;
    t_out[row] = tp;

    uint4* __restrict__ drow = (uint4*)(data16 + (size_t)row * 32);
    #pragma unroll
    for (int g = 0; g < 8; ++g) {
        uint4 pk;
        pk.x = pack_h2(acc[8*g+0], acc[8*g+1]);
        pk.y = pack_h2(acc[8*g+2], acc[8*g+3]);
        pk.z = pack_h2(acc[8*g+4], acc[8*g+5]);
        pk.w = pack_h2(acc[8*g+6], acc[8*g+7]);
        drow[g] = pk;
    }
}

// ---------------------------------------------------------------------------
// bin1: edges -> 98 coarse regions (write-local) + global sub-bucket counts
// (64-node sub-buckets). Record = (u_local10 << 17) | e1
// ---------------------------------------------------------------------------
__global__ __launch_bounds__(1024) void bin1_kernel(
    const int* __restrict__ e0a, const int* __restrict__ e1a,
    int* __restrict__ cursor1, int* __restrict__ subcnt,
    unsigned int* __restrict__ region1, int ne)
{
    __shared__ int cnt[128];
    __shared__ int basev[128];
    __shared__ int scnt[NSB];

    const int tid  = threadIdx.x;
    const int base = blockIdx.x * CHUNK1;

    if (tid < 128) cnt[tid] = 0;
    for (int i = tid; i < NSB; i += 1024) scnt[i] = 0;
    __syncthreads();

    int bj[2]; unsigned rc[2];
    #pragma unroll
    for (int j = 0; j < 2; ++j) {
        const int i = base + j * 1024 + tid;
        if (i < ne) {
            const int u = e0a[i];
            const int v = e1a[i];
            bj[j] = u >> 10;
            rc[j] = ((unsigned)(u & (CB_NODES - 1)) << 17) | (unsigned)v;
            atomicAdd(&cnt[bj[j]], 1);
            atomicAdd(&scnt[u >> 6], 1);
        } else bj[j] = -1;
    }
    __syncthreads();

    if (tid < 128) {
        const int c = cnt[tid];
        basev[tid] = (c > 0) ? atomicAdd(&cursor1[tid], c) : 0;
        cnt[tid] = 0;
    }
    for (int i = tid; i < NSB; i += 1024) {
        const int c = scnt[i];
        if (c > 0) atomicAdd(&subcnt[i], c);
    }
    __syncthreads();

    #pragma unroll
    for (int j = 0; j < 2; ++j) {
        if (bj[j] >= 0) {
            const int p = basev[bj[j]] + atomicAdd(&cnt[bj[j]], 1);
            if (p < CAP1) region1[(size_t)bj[j] * CAP1 + p] = rc[j];
        }
    }
}

// ---------------------------------------------------------------------------
// sbase: exclusive scan of subcnt[1568] (one 1024-thread block, 2 items/thr).
// ---------------------------------------------------------------------------
__global__ __launch_bounds__(1024) void sbase_kernel(
    const int* __restrict__ subcnt, int* __restrict__ sbase)
{
    __shared__ int wsum[16];
    const int tid  = threadIdx.x;
    const int lane = tid & 63;
    const int wv   = tid >> 6;

    const int i0 = tid * 2;
    const int v0 = (i0 + 0 < NSB) ? subcnt[i0 + 0] : 0;
    const int v1 = (i0 + 1 < NSB) ? subcnt[i0 + 1] : 0;
    const int tsum = v0 + v1;

    int x = tsum;
    #pragma unroll
    for (int off = 1; off < 64; off <<= 1) {
        int y = __shfl_up(x, off);
        if (lane >= off) x += y;
    }
    if (lane == 63) wsum[wv] = x;
    __syncthreads();
    if (wv == 0) {
        const int wval = (lane < 16) ? wsum[lane] : 0;
        int wx = wval;
        #pragma unroll
        for (int off = 1; off < 16; off <<= 1) {
            int y = __shfl_up(wx, off);
            if (lane >= off) wx += y;
        }
        if (lane < 16) wsum[lane] = wx - wval;
    }
    __syncthreads();
    const int excl = wsum[wv] + x - tsum;
    if (i0 + 0 < NSB) sbase[i0 + 0] = excl;
    if (i0 + 1 < NSB) sbase[i0 + 1] = excl + v0;
}

// ---------------------------------------------------------------------------
// csr: one 256-thread block per 64-node sub-bucket. XCD-aware remap keeps
// all 16 sub-blocks of a coarse bucket on one XCD (L2 locality).
// Filters its coarse region, builds per-node CSR + fp16 weights + winv.
// ---------------------------------------------------------------------------
__global__ __launch_bounds__(256) void csr_kernel(
    const int* __restrict__ cursor1, const unsigned int* __restrict__ region1,
    const int* __restrict__ sbase,
    const float* __restrict__ s, const float* __restrict__ t,
    int* __restrict__ counts, int* __restrict__ offs,
    float* __restrict__ winv,
    int* __restrict__ se1, __half* __restrict__ wgt, int n)
{
    __shared__ int   lcnt[SB_NODES];
    __shared__ int   loff[SB_NODES];
    __shared__ float wacc[SB_NODES];
    __shared__ float s_lds[SB_NODES];

    // XCD-aware block remap: xcd = b & 7
    const int xcd = blockIdx.x & 7;
    const int idx = blockIdx.x >> 3;           // 0 .. 207
    const int b   = xcd + 8 * (idx >> 4);
    if (b >= NB1) return;
    const unsigned q = (unsigned)(idx & 15);
    const int sb  = b * 16 + (int)q;
    const int tid = threadIdx.x;
    const int u0  = sb << 6;

    const int cnt1 = min(cursor1[b], CAP1);
    const unsigned int* __restrict__ reg = region1 + (size_t)b * CAP1;

    if (tid < SB_NODES) {
        lcnt[tid] = 0;
        wacc[tid] = 0.f;
        const int u = u0 + tid;
        s_lds[tid] = (u < n) ? s[u] : 0.f;
    }
    __syncthreads();

    // pass 1: histogram (filter: ul10 bits [9:6] == q)
    for (int i = tid; i < cnt1; i += 256) {
        const unsigned r = reg[i];
        if ((r >> 23) == q)
            atomicAdd(&lcnt[(r >> 17) & (SB_NODES - 1)], 1);
    }
    __syncthreads();

    // single-wave exclusive scan of lcnt[64]
    if (tid < 64) {
        const int d = lcnt[tid];
        int x = d;
        #pragma unroll
        for (int off = 1; off < 64; off <<= 1) {
            int y = __shfl_up(x, off);
            if (tid >= off) x += y;
        }
        loff[tid] = x - d;
        lcnt[tid] = 0;
    }
    __syncthreads();

    const int base = sbase[sb];

    // pass 2: scatter + weight
    for (int i = tid; i < cnt1; i += 256) {
        const unsigned r = reg[i];
        if ((r >> 23) != q) continue;
        const int ul = (int)((r >> 17) & (SB_NODES - 1));
        const int v  = (int)(r & 0x1FFFFu);
        const float raw = s_lds[ul] + t[v];
        const float lr  = raw > 0.f ? raw : 0.2f * raw;
        const __half wh = __float2half(__expf(lr * 0.125f));
        atomicAdd(&wacc[ul], __half2float(wh));
        const int p = base + loff[ul] + atomicAdd(&lcnt[ul], 1);
        se1[p] = v;
        wgt[p] = wh;
    }
    __syncthreads();

    if (tid < SB_NODES) {
        const int u = u0 + tid;
        if (u < n) {
            const int deg = loff[tid] + lcnt[tid] - loff[tid]; // = lcnt[tid]
            counts[u] = lcnt[tid];
            offs[u]   = base + loff[tid];
            winv[u]   = (lcnt[tid] > 0) ? 1.0f / wacc[tid] : 0.f;
            (void)deg;
        }
    }
}

// ---------------------------------------------------------------------------
// Node aggregation: wave per node; lanes 0-31 = even edge, 32-63 = odd edge;
// each lane holds a half2 feature pair. fp16 data gather (128 B/edge-row).
// ---------------------------------------------------------------------------
__global__ __launch_bounds__(256) void node_kernel(
    const int* __restrict__ se1, const __half* __restrict__ wgt,
    const int* __restrict__ offs, const int* __restrict__ counts,
    const float* __restrict__ winv,
    const __half2* __restrict__ data16, float* __restrict__ out, int n)
{
    const int wave = threadIdx.x >> 6;
    const int lane = threadIdx.x & 63;
    const int half = lane >> 5;
    const int c2   = lane & 31;
    const int u = blockIdx.x * 4 + wave;
    if (u >= n) return;

    const int start = offs[u];
    const int deg   = counts[u];

    float ax = 0.f, ay = 0.f;

    int j = 0;
    for (; j + 8 <= deg; j += 8) {
        const int e0 = start + j + half;
        const int v0 = se1[e0];
        const int v1 = se1[e0 + 2];
        const int v2 = se1[e0 + 4];
        const int v3 = se1[e0 + 6];
        const float w0 = __half2float(wgt[e0]);
        const float w1 = __half2float(wgt[e0 + 2]);
        const float w2 = __half2float(wgt[e0 + 4]);
        const float w3 = __half2float(wgt[e0 + 6]);
        const float2 f0 = __half22float2(data16[(size_t)v0 * 32 + c2]);
        const float2 f1 = __half22float2(data16[(size_t)v1 * 32 + c2]);
        const float2 f2 = __half22float2(data16[(size_t)v2 * 32 + c2]);
        const float2 f3 = __half22float2(data16[(size_t)v3 * 32 + c2]);
        ax = fmaf(w0, f0.x, ax); ay = fmaf(w0, f0.y, ay);
        ax = fmaf(w1, f1.x, ax); ay = fmaf(w1, f1.y, ay);
        ax = fmaf(w2, f2.x, ax); ay = fmaf(w2, f2.y, ay);
        ax = fmaf(w3, f3.x, ax); ay = fmaf(w3, f3.y, ay);
    }
    for (; j < deg; j += 2) {
        if (j + half < deg) {
            const int e = start + j + half;
            const int v = se1[e];
            const float w = __half2float(wgt[e]);
            const float2 f = __half22float2(data16[(size_t)v * 32 + c2]);
            ax = fmaf(w, f.x, ax); ay = fmaf(w, f.y, ay);
        }
    }

    ax += __shfl_xor(ax, 32);
    ay += __shfl_xor(ay, 32);

    if (half == 0) {
        float2 o;
        if (deg == 0) {
            o = __half22float2(data16[(size_t)u * 32 + c2]);
        } else {
            const float wi = winv[u];
            o = make_float2(ax * wi, ay * wi);
        }
        ((float2*)out)[(size_t)u * 32 + c2] = o;
    }
}

extern "C" void kernel_launch(void* const* d_in, const int* in_sizes, int n_in,
                              void* d_out, int out_size, void* d_ws, size_t ws_size,
                              hipStream_t stream)
{
    const float* h    = (const float*)d_in[0];
    const int*   edge = (const int*)d_in[1];
    const float* Ww   = (const float*)d_in[2];
    const float* Wb   = (const float*)d_in[3];
    const float* a    = (const float*)d_in[4];

    const int n  = in_sizes[0] / D_IN;    // 100000
    const int ne = in_sizes[1] / 2;       // 1600000

    const int* e0a = edge;
    const int* e1a = edge + ne;
    float* out = (float*)d_out;

    char* wsp = (char*)d_ws;
    unsigned* data16 = (unsigned*)wsp; wsp += (size_t)n * 32 * sizeof(unsigned); // 64 fp16/row
    float* s       = (float*)wsp;  wsp += (size_t)n * sizeof(float);
    float* t       = (float*)wsp;  wsp += (size_t)n * sizeof(float);
    int*   counts  = (int*)wsp;    wsp += (size_t)n * sizeof(int);
    int*   offs    = (int*)wsp;    wsp += (size_t)n * sizeof(int);
    float* winv    = (float*)wsp;  wsp += (size_t)n * sizeof(float);
    int*   cursor1 = (int*)wsp;    wsp += 128 * sizeof(int);
    int*   subcnt  = (int*)wsp;    wsp += 2048 * sizeof(int);
    int*   sbase   = (int*)wsp;    wsp += 2048 * sizeof(int);
    float* wT      = (float*)wsp;  wsp += (size_t)D_IN * D_OUT * sizeof(float);
    unsigned int* region1 = (unsigned int*)wsp; wsp += (size_t)NB1 * CAP1 * sizeof(unsigned int);
    int*    se1    = (int*)wsp;    wsp += (size_t)ne * sizeof(int);
    __half* wgt    = (__half*)wsp; wsp += (size_t)ne * sizeof(__half);

    hipMemsetAsync(cursor1, 0, (128 + 2048) * sizeof(int), stream);

    wprep_kernel<<<(D_IN * D_OUT + 255) / 256, 256, 0, stream>>>(Ww, wT);

    proj_kernel<<<(n + 255) / 256, 256, 0, stream>>>(
        h, wT, Wb, a, data16, s, t, n);

    bin1_kernel<<<(ne + CHUNK1 - 1) / CHUNK1, 1024, 0, stream>>>(
        e0a, e1a, cursor1, subcnt, region1, ne);

    sbase_kernel<<<1, 1024, 0, stream>>>(subcnt, sbase);

    // 8 XCD slots x 13 bucket-groups x 16 sub-buckets = 1664 blocks (some exit)
    csr_kernel<<<8 * 13 * 16, 256, 0, stream>>>(
        cursor1, region1, sbase, s, t, counts, offs, winv, se1, wgt, n);

    node_kernel<<<(n + 3) / 4, 256, 0, stream>>>(
        se1, wgt, offs, counts, winv, (const __half2*)data16, out, n);
}

// Round 11
// 165.004 us; speedup vs baseline: 1.2413x; 1.1693x over previous
//
#include <hip/hip_runtime.h>
#include <hip/hip_bf16.h>
#include <hip/hip_fp16.h>

#define D_IN   128
#define D_OUT  64

#define SB_NODES  64       // nodes per (fine) sub-bucket
#define NSB       1568     // ceil(100000/64) = 1563, padded to 1568
#define CAP2      1280     // region slots (mean 1024, +8 sigma)
#define CHUNK1    2048     // edges per bin1 block (1024 thr x 2)

static __device__ __forceinline__ unsigned pack_h2(float a, float b) {
    __half2 h = __floats2half2_rn(a, b);
    return *reinterpret_cast<unsigned*>(&h);
}

// ---------------------------------------------------------------------------
// W prep: wT[k][c] = W[c][k]
// ---------------------------------------------------------------------------
__global__ __launch_bounds__(256) void wprep_kernel(
    const float* __restrict__ Ww, float* __restrict__ wT)
{
    const int i = blockIdx.x * 256 + threadIdx.x;
    if (i < D_IN * D_OUT) {
        const int k = i >> 6;
        const int c = i & 63;
        wT[i] = Ww[c * D_IN + k];
    }
}

// ---------------------------------------------------------------------------
// Projection: lane-per-row, scalar-pipe weights. Writes fp16 data16.
// ---------------------------------------------------------------------------
__global__ __launch_bounds__(256, 4) void proj_kernel(
    const float* __restrict__ h, const float* __restrict__ wT,
    const float* __restrict__ Wb, const float* __restrict__ a,
    unsigned* __restrict__ data16, float* __restrict__ s_out, float* __restrict__ t_out,
    int n)
{
    const int row = blockIdx.x * 256 + threadIdx.x;
    if (row >= n) return;

    const float4* __restrict__ hrow = (const float4*)(h + (size_t)row * D_IN);

    float acc[D_OUT];
    #pragma unroll
    for (int c = 0; c < D_OUT; ++c) acc[c] = Wb[c];

    #pragma unroll 1
    for (int ch = 0; ch < 4; ++ch) {
        float4 hq[8];
        #pragma unroll
        for (int q = 0; q < 8; ++q) hq[q] = hrow[ch * 8 + q];

        #pragma unroll
        for (int q = 0; q < 8; ++q) {
            const float hv0 = hq[q].x, hv1 = hq[q].y, hv2 = hq[q].z, hv3 = hq[q].w;
            const int k0 = ch * 32 + q * 4;
            const float* __restrict__ w0 = wT + (size_t)(k0 + 0) * D_OUT;
            const float* __restrict__ w1 = wT + (size_t)(k0 + 1) * D_OUT;
            const float* __restrict__ w2 = wT + (size_t)(k0 + 2) * D_OUT;
            const float* __restrict__ w3 = wT + (size_t)(k0 + 3) * D_OUT;
            #pragma unroll
            for (int c = 0; c < D_OUT; ++c)
                acc[c] = fmaf(hv3, w3[c],
                         fmaf(hv2, w2[c],
                         fmaf(hv1, w1[c],
                         fmaf(hv0, w0[c], acc[c]))));
        }
    }

    float sp = 0.f, tp = 0.f;
    #pragma unroll
    for (int c = 0; c < D_OUT; ++c) {
        sp = fmaf(acc[c], a[c], sp);
        tp = fmaf(acc[c], a[D_OUT + c], tp);
    }
    s_out[row] = sp;
    t_out[row] = tp;

    uint4* __restrict__ drow = (uint4*)(data16 + (size_t)row * 32);
    #pragma unroll
    for (int g = 0; g < 8; ++g) {
        uint4 pk;
        pk.x = pack_h2(acc[8*g+0], acc[8*g+1]);
        pk.y = pack_h2(acc[8*g+2], acc[8*g+3]);
        pk.z = pack_h2(acc[8*g+4], acc[8*g+5]);
        pk.w = pack_h2(acc[8*g+6], acc[8*g+7]);
        drow[g] = pk;
    }
}

// ---------------------------------------------------------------------------
// bin1: edges -> 1568 fine regions directly. Record = (u&63)<<17 | e1.
// Active write frontier = 1568 partially-filled lines (~100 KB) -> L2-resident.
// ---------------------------------------------------------------------------
__global__ __launch_bounds__(1024) void bin1_kernel(
    const int* __restrict__ e0a, const int* __restrict__ e1a,
    int* __restrict__ cursor2, unsigned int* __restrict__ region2, int ne)
{
    __shared__ int cnt[NSB];
    __shared__ int basev[NSB];

    const int tid  = threadIdx.x;
    const int base = blockIdx.x * CHUNK1;

    for (int i = tid; i < NSB; i += 1024) cnt[i] = 0;
    __syncthreads();

    int bj[2]; unsigned rc[2];
    #pragma unroll
    for (int j = 0; j < 2; ++j) {
        const int i = base + j * 1024 + tid;
        if (i < ne) {
            const int u = e0a[i];
            const int v = e1a[i];
            bj[j] = u >> 6;
            rc[j] = ((unsigned)(u & (SB_NODES - 1)) << 17) | (unsigned)v;
            atomicAdd(&cnt[bj[j]], 1);
        } else bj[j] = -1;
    }
    __syncthreads();

    for (int i = tid; i < NSB; i += 1024) {
        const int c = cnt[i];
        basev[i] = (c > 0) ? atomicAdd(&cursor2[i], c) : 0;
        cnt[i] = 0;
    }
    __syncthreads();

    #pragma unroll
    for (int j = 0; j < 2; ++j) {
        if (bj[j] >= 0) {
            const int p = basev[bj[j]] + atomicAdd(&cnt[bj[j]], 1);
            if (p < CAP2) region2[(size_t)bj[j] * CAP2 + p] = rc[j];
        }
    }
}

// ---------------------------------------------------------------------------
// sbase: exclusive scan of min(cursor2[1568], CAP2).
// ---------------------------------------------------------------------------
__global__ __launch_bounds__(1024) void sbase_kernel(
    const int* __restrict__ cursor2, int* __restrict__ sbase)
{
    __shared__ int wsum[16];
    const int tid  = threadIdx.x;
    const int lane = tid & 63;
    const int wv   = tid >> 6;

    const int i0 = tid * 2;
    const int v0 = (i0 + 0 < NSB) ? min(cursor2[i0 + 0], CAP2) : 0;
    const int v1 = (i0 + 1 < NSB) ? min(cursor2[i0 + 1], CAP2) : 0;
    const int tsum = v0 + v1;

    int x = tsum;
    #pragma unroll
    for (int off = 1; off < 64; off <<= 1) {
        int y = __shfl_up(x, off);
        if (lane >= off) x += y;
    }
    if (lane == 63) wsum[wv] = x;
    __syncthreads();
    if (wv == 0) {
        const int wval = (lane < 16) ? wsum[lane] : 0;
        int wx = wval;
        #pragma unroll
        for (int off = 1; off < 16; off <<= 1) {
            int y = __shfl_up(wx, off);
            if (lane >= off) wx += y;
        }
        if (lane < 16) wsum[lane] = wx - wval;
    }
    __syncthreads();
    const int excl = wsum[wv] + x - tsum;
    if (i0 + 0 < NSB) sbase[i0 + 0] = excl;
    if (i0 + 1 < NSB) sbase[i0 + 1] = excl + v0;
}

// ---------------------------------------------------------------------------
// csr: one 256-thread block per fine region. Stages its ~5 KB region in LDS
// (histogram fused), 64-entry scan, weights + scatter from LDS.
// ---------------------------------------------------------------------------
__global__ __launch_bounds__(256) void csr_kernel(
    const int* __restrict__ cursor2, const unsigned int* __restrict__ region2,
    const int* __restrict__ sbase,
    const float* __restrict__ s, const float* __restrict__ t,
    int* __restrict__ counts, int* __restrict__ offs,
    float* __restrict__ winv,
    int* __restrict__ se1, __half* __restrict__ wgt, int n)
{
    __shared__ unsigned rrec[CAP2];
    __shared__ int   lcnt[SB_NODES];
    __shared__ int   loff[SB_NODES];
    __shared__ float wacc[SB_NODES];
    __shared__ float s_lds[SB_NODES];

    const int sb  = blockIdx.x;
    const int tid = threadIdx.x;
    const int u0  = sb << 6;

    const int cnt2 = min(cursor2[sb], CAP2);
    const unsigned int* __restrict__ reg = region2 + (size_t)sb * CAP2;

    if (tid < SB_NODES) {
        lcnt[tid] = 0;
        wacc[tid] = 0.f;
        const int u = u0 + tid;
        s_lds[tid] = (u < n) ? s[u] : 0.f;
    }
    __syncthreads();

    // single global pass: stage + histogram
    for (int i = tid; i < cnt2; i += 256) {
        const unsigned r = reg[i];
        rrec[i] = r;
        atomicAdd(&lcnt[r >> 17], 1);
    }
    __syncthreads();

    // single-wave exclusive scan of lcnt[64]
    if (tid < 64) {
        const int d = lcnt[tid];
        int x = d;
        #pragma unroll
        for (int off = 1; off < 64; off <<= 1) {
            int y = __shfl_up(x, off);
            if (tid >= off) x += y;
        }
        loff[tid] = x - d;
        lcnt[tid] = 0;
    }
    __syncthreads();

    const int base = sbase[sb];

    // pass 2 (from LDS): weight + scatter
    for (int i = tid; i < cnt2; i += 256) {
        const unsigned r = rrec[i];
        const int ul = (int)(r >> 17);
        const int v  = (int)(r & 0x1FFFFu);
        const float raw = s_lds[ul] + t[v];
        const float lr  = raw > 0.f ? raw : 0.2f * raw;
        const __half wh = __float2half(__expf(lr * 0.125f));
        atomicAdd(&wacc[ul], __half2float(wh));
        const int p = base + loff[ul] + atomicAdd(&lcnt[ul], 1);
        se1[p] = v;
        wgt[p] = wh;
    }
    __syncthreads();

    if (tid < SB_NODES) {
        const int u = u0 + tid;
        if (u < n) {
            counts[u] = lcnt[tid];
            offs[u]   = base + loff[tid];
            winv[u]   = (lcnt[tid] > 0) ? 1.0f / wacc[tid] : 0.f;
        }
    }
}

// ---------------------------------------------------------------------------
// Node aggregation: wave per node; lanes 0-31 = even edge, 32-63 = odd edge;
// each lane holds a half2 feature pair. fp16 data gather (128 B/edge-row).
// ---------------------------------------------------------------------------
__global__ __launch_bounds__(256) void node_kernel(
    const int* __restrict__ se1, const __half* __restrict__ wgt,
    const int* __restrict__ offs, const int* __restrict__ counts,
    const float* __restrict__ winv,
    const __half2* __restrict__ data16, float* __restrict__ out, int n)
{
    const int wave = threadIdx.x >> 6;
    const int lane = threadIdx.x & 63;
    const int half = lane >> 5;
    const int c2   = lane & 31;
    const int u = blockIdx.x * 4 + wave;
    if (u >= n) return;

    const int start = offs[u];
    const int deg   = counts[u];

    float ax = 0.f, ay = 0.f;

    int j = 0;
    for (; j + 8 <= deg; j += 8) {
        const int e0 = start + j + half;
        const int v0 = se1[e0];
        const int v1 = se1[e0 + 2];
        const int v2 = se1[e0 + 4];
        const int v3 = se1[e0 + 6];
        const float w0 = __half2float(wgt[e0]);
        const float w1 = __half2float(wgt[e0 + 2]);
        const float w2 = __half2float(wgt[e0 + 4]);
        const float w3 = __half2float(wgt[e0 + 6]);
        const float2 f0 = __half22float2(data16[(size_t)v0 * 32 + c2]);
        const float2 f1 = __half22float2(data16[(size_t)v1 * 32 + c2]);
        const float2 f2 = __half22float2(data16[(size_t)v2 * 32 + c2]);
        const float2 f3 = __half22float2(data16[(size_t)v3 * 32 + c2]);
        ax = fmaf(w0, f0.x, ax); ay = fmaf(w0, f0.y, ay);
        ax = fmaf(w1, f1.x, ax); ay = fmaf(w1, f1.y, ay);
        ax = fmaf(w2, f2.x, ax); ay = fmaf(w2, f2.y, ay);
        ax = fmaf(w3, f3.x, ax); ay = fmaf(w3, f3.y, ay);
    }
    for (; j < deg; j += 2) {
        if (j + half < deg) {
            const int e = start + j + half;
            const int v = se1[e];
            const float w = __half2float(wgt[e]);
            const float2 f = __half22float2(data16[(size_t)v * 32 + c2]);
            ax = fmaf(w, f.x, ax); ay = fmaf(w, f.y, ay);
        }
    }

    ax += __shfl_xor(ax, 32);
    ay += __shfl_xor(ay, 32);

    if (half == 0) {
        float2 o;
        if (deg == 0) {
            o = __half22float2(data16[(size_t)u * 32 + c2]);
        } else {
            const float wi = winv[u];
            o = make_float2(ax * wi, ay * wi);
        }
        ((float2*)out)[(size_t)u * 32 + c2] = o;
    }
}

extern "C" void kernel_launch(void* const* d_in, const int* in_sizes, int n_in,
                              void* d_out, int out_size, void* d_ws, size_t ws_size,
                              hipStream_t stream)
{
    const float* h    = (const float*)d_in[0];
    const int*   edge = (const int*)d_in[1];
    const float* Ww   = (const float*)d_in[2];
    const float* Wb   = (const float*)d_in[3];
    const float* a    = (const float*)d_in[4];

    const int n  = in_sizes[0] / D_IN;    // 100000
    const int ne = in_sizes[1] / 2;       // 1600000

    const int* e0a = edge;
    const int* e1a = edge + ne;
    float* out = (float*)d_out;

    char* wsp = (char*)d_ws;
    unsigned* data16 = (unsigned*)wsp; wsp += (size_t)n * 32 * sizeof(unsigned); // 64 fp16/row
    float* s       = (float*)wsp;  wsp += (size_t)n * sizeof(float);
    float* t       = (float*)wsp;  wsp += (size_t)n * sizeof(float);
    int*   counts  = (int*)wsp;    wsp += (size_t)n * sizeof(int);
    int*   offs    = (int*)wsp;    wsp += (size_t)n * sizeof(int);
    float* winv    = (float*)wsp;  wsp += (size_t)n * sizeof(float);
    int*   cursor2 = (int*)wsp;    wsp += 2048 * sizeof(int);
    int*   sbase   = (int*)wsp;    wsp += 2048 * sizeof(int);
    float* wT      = (float*)wsp;  wsp += (size_t)D_IN * D_OUT * sizeof(float);
    unsigned int* region2 = (unsigned int*)wsp; wsp += (size_t)NSB * CAP2 * sizeof(unsigned int);
    int*    se1    = (int*)wsp;    wsp += (size_t)ne * sizeof(int);
    __half* wgt    = (__half*)wsp; wsp += (size_t)ne * sizeof(__half);

    hipMemsetAsync(cursor2, 0, 2048 * sizeof(int), stream);

    wprep_kernel<<<(D_IN * D_OUT + 255) / 256, 256, 0, stream>>>(Ww, wT);

    proj_kernel<<<(n + 255) / 256, 256, 0, stream>>>(
        h, wT, Wb, a, data16, s, t, n);

    bin1_kernel<<<(ne + CHUNK1 - 1) / CHUNK1, 1024, 0, stream>>>(
        e0a, e1a, cursor2, region2, ne);

    sbase_kernel<<<1, 1024, 0, stream>>>(cursor2, sbase);

    csr_kernel<<<NSB, 256, 0, stream>>>(
        cursor2, region2, sbase, s, t, counts, offs, winv, se1, wgt, n);

    node_kernel<<<(n + 3) / 4, 256, 0, stream>>>(
        se1, wgt, offs, counts, winv, (const __half2*)data16, out, n);
}

// Round 12
// 138.869 us; speedup vs baseline: 1.4749x; 1.1882x over previous
//
#include <hip/hip_runtime.h>
#include <hip/hip_bf16.h>
#include <hip/hip_fp16.h>

#define D_IN   128
#define D_OUT  64

#define SB_NODES  64       // nodes per (fine) sub-bucket
#define NSB       1568     // ceil(100000/64) = 1563, padded
#define CAP2      1280     // region slots (mean 1024, +8 sigma)
#define CHUNK1    2048     // edges per bin1 block (1024 thr x 2)

static __device__ __forceinline__ unsigned pack_h2(float a, float b) {
    __half2 h = __floats2half2_rn(a, b);
    return *reinterpret_cast<unsigned*>(&h);
}

// ---------------------------------------------------------------------------
// W prep: wT[k][c] = W[c][k]
// ---------------------------------------------------------------------------
__global__ __launch_bounds__(256) void wprep_kernel(
    const float* __restrict__ Ww, float* __restrict__ wT)
{
    const int i = blockIdx.x * 256 + threadIdx.x;
    if (i < D_IN * D_OUT) {
        const int k = i >> 6;
        const int c = i & 63;
        wT[i] = Ww[c * D_IN + k];
    }
}

// ---------------------------------------------------------------------------
// Projection: lane-per-row, scalar-pipe weights. Writes fp16 data16.
// ---------------------------------------------------------------------------
__global__ __launch_bounds__(256, 4) void proj_kernel(
    const float* __restrict__ h, const float* __restrict__ wT,
    const float* __restrict__ Wb, const float* __restrict__ a,
    unsigned* __restrict__ data16, float* __restrict__ s_out, float* __restrict__ t_out,
    int n)
{
    const int row = blockIdx.x * 256 + threadIdx.x;
    if (row >= n) return;

    const float4* __restrict__ hrow = (const float4*)(h + (size_t)row * D_IN);

    float acc[D_OUT];
    #pragma unroll
    for (int c = 0; c < D_OUT; ++c) acc[c] = Wb[c];

    #pragma unroll 1
    for (int ch = 0; ch < 4; ++ch) {
        float4 hq[8];
        #pragma unroll
        for (int q = 0; q < 8; ++q) hq[q] = hrow[ch * 8 + q];

        #pragma unroll
        for (int q = 0; q < 8; ++q) {
            const float hv0 = hq[q].x, hv1 = hq[q].y, hv2 = hq[q].z, hv3 = hq[q].w;
            const int k0 = ch * 32 + q * 4;
            const float* __restrict__ w0 = wT + (size_t)(k0 + 0) * D_OUT;
            const float* __restrict__ w1 = wT + (size_t)(k0 + 1) * D_OUT;
            const float* __restrict__ w2 = wT + (size_t)(k0 + 2) * D_OUT;
            const float* __restrict__ w3 = wT + (size_t)(k0 + 3) * D_OUT;
            #pragma unroll
            for (int c = 0; c < D_OUT; ++c)
                acc[c] = fmaf(hv3, w3[c],
                         fmaf(hv2, w2[c],
                         fmaf(hv1, w1[c],
                         fmaf(hv0, w0[c], acc[c]))));
        }
    }

    float sp = 0.f, tp = 0.f;
    #pragma unroll
    for (int c = 0; c < D_OUT; ++c) {
        sp = fmaf(acc[c], a[c], sp);
        tp = fmaf(acc[c], a[D_OUT + c], tp);
    }
    s_out[row] = sp;
    t_out[row] = tp;

    uint4* __restrict__ drow = (uint4*)(data16 + (size_t)row * 32);
    #pragma unroll
    for (int g = 0; g < 8; ++g) {
        uint4 pk;
        pk.x = pack_h2(acc[8*g+0], acc[8*g+1]);
        pk.y = pack_h2(acc[8*g+2], acc[8*g+3]);
        pk.z = pack_h2(acc[8*g+4], acc[8*g+5]);
        pk.w = pack_h2(acc[8*g+6], acc[8*g+7]);
        drow[g] = pk;
    }
}

// ---------------------------------------------------------------------------
// bin1: edges -> 1568 fine regions directly. Record = (u&63)<<17 | e1.
// ---------------------------------------------------------------------------
__global__ __launch_bounds__(1024) void bin1_kernel(
    const int* __restrict__ e0a, const int* __restrict__ e1a,
    int* __restrict__ cursor2, unsigned int* __restrict__ region2, int ne)
{
    __shared__ int cnt[NSB];
    __shared__ int basev[NSB];

    const int tid  = threadIdx.x;
    const int base = blockIdx.x * CHUNK1;

    for (int i = tid; i < NSB; i += 1024) cnt[i] = 0;
    __syncthreads();

    int bj[2]; unsigned rc[2];
    #pragma unroll
    for (int j = 0; j < 2; ++j) {
        const int i = base + j * 1024 + tid;
        if (i < ne) {
            const int u = e0a[i];
            const int v = e1a[i];
            bj[j] = u >> 6;
            rc[j] = ((unsigned)(u & (SB_NODES - 1)) << 17) | (unsigned)v;
            atomicAdd(&cnt[bj[j]], 1);
        } else bj[j] = -1;
    }
    __syncthreads();

    for (int i = tid; i < NSB; i += 1024) {
        const int c = cnt[i];
        basev[i] = (c > 0) ? atomicAdd(&cursor2[i], c) : 0;
        cnt[i] = 0;
    }
    __syncthreads();

    #pragma unroll
    for (int j = 0; j < 2; ++j) {
        if (bj[j] >= 0) {
            const int p = basev[bj[j]] + atomicAdd(&cnt[bj[j]], 1);
            if (p < CAP2) region2[(size_t)bj[j] * CAP2 + p] = rc[j];
        }
    }
}

// ---------------------------------------------------------------------------
// agg: one 512-thread block per fine bucket. Stage region + weights in LDS,
// per-node LDS scatter, then 8 waves x 8 nodes gather-accumulate. No CSR
// globals at all.
// ---------------------------------------------------------------------------
__global__ __launch_bounds__(512) void agg_kernel(
    const int* __restrict__ cursor2, const unsigned int* __restrict__ region2,
    const float* __restrict__ s, const float* __restrict__ t,
    const __half2* __restrict__ data16, float* __restrict__ out, int n)
{
    __shared__ unsigned       rrec[CAP2];
    __shared__ unsigned short rwh[CAP2];
    __shared__ int            sv[CAP2];
    __shared__ unsigned short sw[CAP2];
    __shared__ int   lcnt[SB_NODES];
    __shared__ int   loff[SB_NODES];
    __shared__ float wacc[SB_NODES];
    __shared__ float s_lds[SB_NODES];

    const int sb  = blockIdx.x;
    const int tid = threadIdx.x;
    const int u0  = sb << 6;
    if (u0 >= n) return;                       // uniform per block

    const int cnt2 = min(cursor2[sb], CAP2);
    const unsigned int* __restrict__ reg = region2 + (size_t)sb * CAP2;

    if (tid < SB_NODES) {
        lcnt[tid] = 0;
        wacc[tid] = 0.f;
        const int u = u0 + tid;
        s_lds[tid] = (u < n) ? s[u] : 0.f;
    }
    __syncthreads();

    // pass 1: stage + weight + histogram
    for (int i = tid; i < cnt2; i += 512) {
        const unsigned r = reg[i];
        rrec[i] = r;
        const int ul = (int)(r >> 17);
        const int v  = (int)(r & 0x1FFFFu);
        const float raw = s_lds[ul] + t[v];
        const float lr  = raw > 0.f ? raw : 0.2f * raw;
        const __half wh = __float2half(__expf(lr * 0.125f));
        rwh[i] = __half_as_ushort(wh);
        atomicAdd(&lcnt[ul], 1);
        atomicAdd(&wacc[ul], __half2float(wh));
    }
    __syncthreads();

    // single-wave exclusive scan of lcnt[64]
    if (tid < 64) {
        const int d = lcnt[tid];
        int x = d;
        #pragma unroll
        for (int off = 1; off < 64; off <<= 1) {
            int y = __shfl_up(x, off);
            if (tid >= off) x += y;
        }
        loff[tid] = x - d;
        lcnt[tid] = 0;
    }
    __syncthreads();

    // pass 2: LDS-internal scatter into per-node lists
    for (int i = tid; i < cnt2; i += 512) {
        const unsigned r = rrec[i];
        const int ul = (int)(r >> 17);
        const int p  = loff[ul] + atomicAdd(&lcnt[ul], 1);
        sv[p] = (int)(r & 0x1FFFFu);
        sw[p] = rwh[i];
    }
    __syncthreads();

    // pass 3: 8 waves x 8 nodes gather-accumulate
    const int lane = tid & 63;
    const int wv   = tid >> 6;
    const int half = lane >> 5;
    const int c2   = lane & 31;

    for (int ul = wv * 8; ul < wv * 8 + 8; ++ul) {
        const int u = u0 + ul;
        if (u >= n) break;
        const int start = loff[ul];
        const int deg   = lcnt[ul];

        float ax = 0.f, ay = 0.f;
        int j = 0;
        for (; j + 16 <= deg; j += 16) {
            const int e = start + j + half;
            const int v0 = sv[e +  0], v1 = sv[e +  2], v2 = sv[e +  4], v3 = sv[e +  6];
            const int v4 = sv[e +  8], v5 = sv[e + 10], v6 = sv[e + 12], v7 = sv[e + 14];
            const float w0 = __half2float(__ushort_as_half(sw[e +  0]));
            const float w1 = __half2float(__ushort_as_half(sw[e +  2]));
            const float w2 = __half2float(__ushort_as_half(sw[e +  4]));
            const float w3 = __half2float(__ushort_as_half(sw[e +  6]));
            const float w4 = __half2float(__ushort_as_half(sw[e +  8]));
            const float w5 = __half2float(__ushort_as_half(sw[e + 10]));
            const float w6 = __half2float(__ushort_as_half(sw[e + 12]));
            const float w7 = __half2float(__ushort_as_half(sw[e + 14]));
            const float2 f0 = __half22float2(data16[(size_t)v0 * 32 + c2]);
            const float2 f1 = __half22float2(data16[(size_t)v1 * 32 + c2]);
            const float2 f2 = __half22float2(data16[(size_t)v2 * 32 + c2]);
            const float2 f3 = __half22float2(data16[(size_t)v3 * 32 + c2]);
            const float2 f4 = __half22float2(data16[(size_t)v4 * 32 + c2]);
            const float2 f5 = __half22float2(data16[(size_t)v5 * 32 + c2]);
            const float2 f6 = __half22float2(data16[(size_t)v6 * 32 + c2]);
            const float2 f7 = __half22float2(data16[(size_t)v7 * 32 + c2]);
            ax = fmaf(w0, f0.x, ax); ay = fmaf(w0, f0.y, ay);
            ax = fmaf(w1, f1.x, ax); ay = fmaf(w1, f1.y, ay);
            ax = fmaf(w2, f2.x, ax); ay = fmaf(w2, f2.y, ay);
            ax = fmaf(w3, f3.x, ax); ay = fmaf(w3, f3.y, ay);
            ax = fmaf(w4, f4.x, ax); ay = fmaf(w4, f4.y, ay);
            ax = fmaf(w5, f5.x, ax); ay = fmaf(w5, f5.y, ay);
            ax = fmaf(w6, f6.x, ax); ay = fmaf(w6, f6.y, ay);
            ax = fmaf(w7, f7.x, ax); ay = fmaf(w7, f7.y, ay);
        }
        for (; j + 8 <= deg; j += 8) {
            const int e = start + j + half;
            const int v0 = sv[e + 0], v1 = sv[e + 2], v2 = sv[e + 4], v3 = sv[e + 6];
            const float w0 = __half2float(__ushort_as_half(sw[e + 0]));
            const float w1 = __half2float(__ushort_as_half(sw[e + 2]));
            const float w2 = __half2float(__ushort_as_half(sw[e + 4]));
            const float w3 = __half2float(__ushort_as_half(sw[e + 6]));
            const float2 f0 = __half22float2(data16[(size_t)v0 * 32 + c2]);
            const float2 f1 = __half22float2(data16[(size_t)v1 * 32 + c2]);
            const float2 f2 = __half22float2(data16[(size_t)v2 * 32 + c2]);
            const float2 f3 = __half22float2(data16[(size_t)v3 * 32 + c2]);
            ax = fmaf(w0, f0.x, ax); ay = fmaf(w0, f0.y, ay);
            ax = fmaf(w1, f1.x, ax); ay = fmaf(w1, f1.y, ay);
            ax = fmaf(w2, f2.x, ax); ay = fmaf(w2, f2.y, ay);
            ax = fmaf(w3, f3.x, ax); ay = fmaf(w3, f3.y, ay);
        }
        for (; j < deg; j += 2) {
            if (j + half < deg) {
                const int e = start + j + half;
                const int v = sv[e];
                const float w = __half2float(__ushort_as_half(sw[e]));
                const float2 f = __half22float2(data16[(size_t)v * 32 + c2]);
                ax = fmaf(w, f.x, ax); ay = fmaf(w, f.y, ay);
            }
        }

        ax += __shfl_xor(ax, 32);
        ay += __shfl_xor(ay, 32);

        if (half == 0) {
            float2 o;
            if (deg == 0) {
                o = __half22float2(data16[(size_t)u * 32 + c2]);
            } else {
                const float wi = 1.0f / wacc[ul];
                o = make_float2(ax * wi, ay * wi);
            }
            ((float2*)out)[(size_t)u * 32 + c2] = o;
        }
    }
}

extern "C" void kernel_launch(void* const* d_in, const int* in_sizes, int n_in,
                              void* d_out, int out_size, void* d_ws, size_t ws_size,
                              hipStream_t stream)
{
    const float* h    = (const float*)d_in[0];
    const int*   edge = (const int*)d_in[1];
    const float* Ww   = (const float*)d_in[2];
    const float* Wb   = (const float*)d_in[3];
    const float* a    = (const float*)d_in[4];

    const int n  = in_sizes[0] / D_IN;    // 100000
    const int ne = in_sizes[1] / 2;       // 1600000

    const int* e0a = edge;
    const int* e1a = edge + ne;
    float* out = (float*)d_out;

    char* wsp = (char*)d_ws;
    unsigned* data16 = (unsigned*)wsp; wsp += (size_t)n * 32 * sizeof(unsigned);
    float* s       = (float*)wsp;  wsp += (size_t)n * sizeof(float);
    float* t       = (float*)wsp;  wsp += (size_t)n * sizeof(float);
    int*   cursor2 = (int*)wsp;    wsp += 2048 * sizeof(int);
    float* wT      = (float*)wsp;  wsp += (size_t)D_IN * D_OUT * sizeof(float);
    unsigned int* region2 = (unsigned int*)wsp; wsp += (size_t)NSB * CAP2 * sizeof(unsigned int);

    hipMemsetAsync(cursor2, 0, 2048 * sizeof(int), stream);

    wprep_kernel<<<(D_IN * D_OUT + 255) / 256, 256, 0, stream>>>(Ww, wT);

    proj_kernel<<<(n + 255) / 256, 256, 0, stream>>>(
        h, wT, Wb, a, data16, s, t, n);

    bin1_kernel<<<(ne + CHUNK1 - 1) / CHUNK1, 1024, 0, stream>>>(
        e0a, e1a, cursor2, region2, ne);

    agg_kernel<<<NSB, 512, 0, stream>>>(
        cursor2, region2, s, t, (const __half2*)data16, out, n);
}

// Round 13
// 125.417 us; speedup vs baseline: 1.6331x; 1.1073x over previous
//
#include <hip/hip_runtime.h>
#include <hip/hip_bf16.h>
#include <hip/hip_fp16.h>

#define D_IN   128
#define D_OUT  64

#define SB_NODES  64       // nodes per (fine) sub-bucket
#define NSB       1568     // ceil(100000/64) = 1563, padded
#define CAP2      1280     // region slots (mean 1024, +8 sigma)
#define CHUNK1    2048     // edges per bin1 block (1024 thr x 2)

static __device__ __forceinline__ unsigned pack_h2(float a, float b) {
    __half2 h = __floats2half2_rn(a, b);
    return *reinterpret_cast<unsigned*>(&h);
}

// ---------------------------------------------------------------------------
// W prep: wT[k][c] = W[c][k]
// ---------------------------------------------------------------------------
__global__ __launch_bounds__(256) void wprep_kernel(
    const float* __restrict__ Ww, float* __restrict__ wT)
{
    const int i = blockIdx.x * 256 + threadIdx.x;
    if (i < D_IN * D_OUT) {
        const int k = i >> 6;
        const int c = i & 63;
        wT[i] = Ww[c * D_IN + k];
    }
}

// ---------------------------------------------------------------------------
// Projection: block = 64 rows x 4 waves. Wave q computes output quarter
// [q*16, q*16+16) for all 64 rows (lane = row). q via readfirstlane ->
// weight addresses wave-uniform -> scalar-pipe loads. 4x the wave count
// of the old lane-per-row version (24 waves/CU).
// ---------------------------------------------------------------------------
__global__ __launch_bounds__(256, 6) void proj_kernel(
    const float* __restrict__ h, const float* __restrict__ wT,
    const float* __restrict__ Wb, const float* __restrict__ a,
    unsigned* __restrict__ data16, float* __restrict__ s_out, float* __restrict__ t_out,
    int n)
{
    __shared__ float psum_s[4][64];
    __shared__ float psum_t[4][64];

    const int lane = threadIdx.x & 63;
    const int wv   = threadIdx.x >> 6;
    const int q    = __builtin_amdgcn_readfirstlane(wv);   // wave-uniform
    const int row  = blockIdx.x * 64 + lane;
    const bool live = (row < n);

    const float4* __restrict__ hrow =
        (const float4*)(h + (size_t)(live ? row : 0) * D_IN);

    float acc[16];
    #pragma unroll
    for (int c = 0; c < 16; ++c) acc[c] = Wb[q * 16 + c];

    #pragma unroll 1
    for (int ch = 0; ch < 4; ++ch) {
        float4 hq[8];
        #pragma unroll
        for (int j = 0; j < 8; ++j) hq[j] = hrow[ch * 8 + j];

        #pragma unroll
        for (int j = 0; j < 8; ++j) {
            const float hv0 = hq[j].x, hv1 = hq[j].y, hv2 = hq[j].z, hv3 = hq[j].w;
            const int k0 = ch * 32 + j * 4;
            const float* __restrict__ w0 = wT + (size_t)(k0 + 0) * D_OUT + q * 16;
            const float* __restrict__ w1 = wT + (size_t)(k0 + 1) * D_OUT + q * 16;
            const float* __restrict__ w2 = wT + (size_t)(k0 + 2) * D_OUT + q * 16;
            const float* __restrict__ w3 = wT + (size_t)(k0 + 3) * D_OUT + q * 16;
            #pragma unroll
            for (int c = 0; c < 16; ++c)
                acc[c] = fmaf(hv3, w3[c],
                         fmaf(hv2, w2[c],
                         fmaf(hv1, w1[c],
                         fmaf(hv0, w0[c], acc[c]))));
        }
    }

    // partial s/t over this quarter
    float sp = 0.f, tp = 0.f;
    #pragma unroll
    for (int c = 0; c < 16; ++c) {
        sp = fmaf(acc[c], a[q * 16 + c], sp);
        tp = fmaf(acc[c], a[D_OUT + q * 16 + c], tp);
    }
    psum_s[wv][lane] = sp;
    psum_t[wv][lane] = tp;

    // write this quarter's fp16 (32 B at row*128 + q*32)
    if (live) {
        uint4 pk0, pk1;
        pk0.x = pack_h2(acc[0],  acc[1]);
        pk0.y = pack_h2(acc[2],  acc[3]);
        pk0.z = pack_h2(acc[4],  acc[5]);
        pk0.w = pack_h2(acc[6],  acc[7]);
        pk1.x = pack_h2(acc[8],  acc[9]);
        pk1.y = pack_h2(acc[10], acc[11]);
        pk1.z = pack_h2(acc[12], acc[13]);
        pk1.w = pack_h2(acc[14], acc[15]);
        uint4* __restrict__ dq = (uint4*)(data16 + (size_t)row * 32 + q * 8);
        dq[0] = pk0;
        dq[1] = pk1;
    }

    __syncthreads();
    if (wv == 0 && live) {
        const float ss = psum_s[0][lane] + psum_s[1][lane] + psum_s[2][lane] + psum_s[3][lane];
        const float ts = psum_t[0][lane] + psum_t[1][lane] + psum_t[2][lane] + psum_t[3][lane];
        s_out[row] = ss;
        t_out[row] = ts;
    }
}

// ---------------------------------------------------------------------------
// bin1: edges -> 1568 fine regions directly. Record = (u&63)<<17 | e1.
// ---------------------------------------------------------------------------
__global__ __launch_bounds__(1024) void bin1_kernel(
    const int* __restrict__ e0a, const int* __restrict__ e1a,
    int* __restrict__ cursor2, unsigned int* __restrict__ region2, int ne)
{
    __shared__ int cnt[NSB];
    __shared__ int basev[NSB];

    const int tid  = threadIdx.x;
    const int base = blockIdx.x * CHUNK1;

    for (int i = tid; i < NSB; i += 1024) cnt[i] = 0;
    __syncthreads();

    int bj[2]; unsigned rc[2];
    #pragma unroll
    for (int j = 0; j < 2; ++j) {
        const int i = base + j * 1024 + tid;
        if (i < ne) {
            const int u = e0a[i];
            const int v = e1a[i];
            bj[j] = u >> 6;
            rc[j] = ((unsigned)(u & (SB_NODES - 1)) << 17) | (unsigned)v;
            atomicAdd(&cnt[bj[j]], 1);
        } else bj[j] = -1;
    }
    __syncthreads();

    for (int i = tid; i < NSB; i += 1024) {
        const int c = cnt[i];
        basev[i] = (c > 0) ? atomicAdd(&cursor2[i], c) : 0;
        cnt[i] = 0;
    }
    __syncthreads();

    #pragma unroll
    for (int j = 0; j < 2; ++j) {
        if (bj[j] >= 0) {
            const int p = basev[bj[j]] + atomicAdd(&cnt[bj[j]], 1);
            if (p < CAP2) region2[(size_t)bj[j] * CAP2 + p] = rc[j];
        }
    }
}

// ---------------------------------------------------------------------------
// agg: one 512-thread block per fine bucket. Stage region + weights in LDS,
// per-node LDS scatter, then 8 waves x 8 nodes gather-accumulate.
// ---------------------------------------------------------------------------
__global__ __launch_bounds__(512) void agg_kernel(
    const int* __restrict__ cursor2, const unsigned int* __restrict__ region2,
    const float* __restrict__ s, const float* __restrict__ t,
    const __half2* __restrict__ data16, float* __restrict__ out, int n)
{
    __shared__ unsigned       rrec[CAP2];
    __shared__ unsigned short rwh[CAP2];
    __shared__ int            sv[CAP2];
    __shared__ unsigned short sw[CAP2];
    __shared__ int   lcnt[SB_NODES];
    __shared__ int   loff[SB_NODES];
    __shared__ float wacc[SB_NODES];
    __shared__ float s_lds[SB_NODES];

    const int sb  = blockIdx.x;
    const int tid = threadIdx.x;
    const int u0  = sb << 6;
    if (u0 >= n) return;                       // uniform per block

    const int cnt2 = min(cursor2[sb], CAP2);
    const unsigned int* __restrict__ reg = region2 + (size_t)sb * CAP2;

    if (tid < SB_NODES) {
        lcnt[tid] = 0;
        wacc[tid] = 0.f;
        const int u = u0 + tid;
        s_lds[tid] = (u < n) ? s[u] : 0.f;
    }
    __syncthreads();

    // pass 1: stage + weight + histogram
    for (int i = tid; i < cnt2; i += 512) {
        const unsigned r = reg[i];
        rrec[i] = r;
        const int ul = (int)(r >> 17);
        const int v  = (int)(r & 0x1FFFFu);
        const float raw = s_lds[ul] + t[v];
        const float lr  = raw > 0.f ? raw : 0.2f * raw;
        const __half wh = __float2half(__expf(lr * 0.125f));
        rwh[i] = __half_as_ushort(wh);
        atomicAdd(&lcnt[ul], 1);
        atomicAdd(&wacc[ul], __half2float(wh));
    }
    __syncthreads();

    // single-wave exclusive scan of lcnt[64]
    if (tid < 64) {
        const int d = lcnt[tid];
        int x = d;
        #pragma unroll
        for (int off = 1; off < 64; off <<= 1) {
            int y = __shfl_up(x, off);
            if (tid >= off) x += y;
        }
        loff[tid] = x - d;
        lcnt[tid] = 0;
    }
    __syncthreads();

    // pass 2: LDS-internal scatter into per-node lists
    for (int i = tid; i < cnt2; i += 512) {
        const unsigned r = rrec[i];
        const int ul = (int)(r >> 17);
        const int p  = loff[ul] + atomicAdd(&lcnt[ul], 1);
        sv[p] = (int)(r & 0x1FFFFu);
        sw[p] = rwh[i];
    }
    __syncthreads();

    // pass 3: 8 waves x 8 nodes gather-accumulate
    const int lane = tid & 63;
    const int wv   = tid >> 6;
    const int half = lane >> 5;
    const int c2   = lane & 31;

    for (int ul = wv * 8; ul < wv * 8 + 8; ++ul) {
        const int u = u0 + ul;
        if (u >= n) break;
        const int start = loff[ul];
        const int deg   = lcnt[ul];

        float ax = 0.f, ay = 0.f;
        int j = 0;
        for (; j + 16 <= deg; j += 16) {
            const int e = start + j + half;
            const int v0 = sv[e +  0], v1 = sv[e +  2], v2 = sv[e +  4], v3 = sv[e +  6];
            const int v4 = sv[e +  8], v5 = sv[e + 10], v6 = sv[e + 12], v7 = sv[e + 14];
            const float w0 = __half2float(__ushort_as_half(sw[e +  0]));
            const float w1 = __half2float(__ushort_as_half(sw[e +  2]));
            const float w2 = __half2float(__ushort_as_half(sw[e +  4]));
            const float w3 = __half2float(__ushort_as_half(sw[e +  6]));
            const float w4 = __half2float(__ushort_as_half(sw[e +  8]));
            const float w5 = __half2float(__ushort_as_half(sw[e + 10]));
            const float w6 = __half2float(__ushort_as_half(sw[e + 12]));
            const float w7 = __half2float(__ushort_as_half(sw[e + 14]));
            const float2 f0 = __half22float2(data16[(size_t)v0 * 32 + c2]);
            const float2 f1 = __half22float2(data16[(size_t)v1 * 32 + c2]);
            const float2 f2 = __half22float2(data16[(size_t)v2 * 32 + c2]);
            const float2 f3 = __half22float2(data16[(size_t)v3 * 32 + c2]);
            const float2 f4 = __half22float2(data16[(size_t)v4 * 32 + c2]);
            const float2 f5 = __half22float2(data16[(size_t)v5 * 32 + c2]);
            const float2 f6 = __half22float2(data16[(size_t)v6 * 32 + c2]);
            const float2 f7 = __half22float2(data16[(size_t)v7 * 32 + c2]);
            ax = fmaf(w0, f0.x, ax); ay = fmaf(w0, f0.y, ay);
            ax = fmaf(w1, f1.x, ax); ay = fmaf(w1, f1.y, ay);
            ax = fmaf(w2, f2.x, ax); ay = fmaf(w2, f2.y, ay);
            ax = fmaf(w3, f3.x, ax); ay = fmaf(w3, f3.y, ay);
            ax = fmaf(w4, f4.x, ax); ay = fmaf(w4, f4.y, ay);
            ax = fmaf(w5, f5.x, ax); ay = fmaf(w5, f5.y, ay);
            ax = fmaf(w6, f6.x, ax); ay = fmaf(w6, f6.y, ay);
            ax = fmaf(w7, f7.x, ax); ay = fmaf(w7, f7.y, ay);
        }
        for (; j + 8 <= deg; j += 8) {
            const int e = start + j + half;
            const int v0 = sv[e + 0], v1 = sv[e + 2], v2 = sv[e + 4], v3 = sv[e + 6];
            const float w0 = __half2float(__ushort_as_half(sw[e + 0]));
            const float w1 = __half2float(__ushort_as_half(sw[e + 2]));
            const float w2 = __half2float(__ushort_as_half(sw[e + 4]));
            const float w3 = __half2float(__ushort_as_half(sw[e + 6]));
            const float2 f0 = __half22float2(data16[(size_t)v0 * 32 + c2]);
            const float2 f1 = __half22float2(data16[(size_t)v1 * 32 + c2]);
            const float2 f2 = __half22float2(data16[(size_t)v2 * 32 + c2]);
            const float2 f3 = __half22float2(data16[(size_t)v3 * 32 + c2]);
            ax = fmaf(w0, f0.x, ax); ay = fmaf(w0, f0.y, ay);
            ax = fmaf(w1, f1.x, ax); ay = fmaf(w1, f1.y, ay);
            ax = fmaf(w2, f2.x, ax); ay = fmaf(w2, f2.y, ay);
            ax = fmaf(w3, f3.x, ax); ay = fmaf(w3, f3.y, ay);
        }
        for (; j < deg; j += 2) {
            if (j + half < deg) {
                const int e = start + j + half;
                const int v = sv[e];
                const float w = __half2float(__ushort_as_half(sw[e]));
                const float2 f = __half22float2(data16[(size_t)v * 32 + c2]);
                ax = fmaf(w, f.x, ax); ay = fmaf(w, f.y, ay);
            }
        }

        ax += __shfl_xor(ax, 32);
        ay += __shfl_xor(ay, 32);

        if (half == 0) {
            float2 o;
            if (deg == 0) {
                o = __half22float2(data16[(size_t)u * 32 + c2]);
            } else {
                const float wi = 1.0f / wacc[ul];
                o = make_float2(ax * wi, ay * wi);
            }
            ((float2*)out)[(size_t)u * 32 + c2] = o;
        }
    }
}

extern "C" void kernel_launch(void* const* d_in, const int* in_sizes, int n_in,
                              void* d_out, int out_size, void* d_ws, size_t ws_size,
                              hipStream_t stream)
{
    const float* h    = (const float*)d_in[0];
    const int*   edge = (const int*)d_in[1];
    const float* Ww   = (const float*)d_in[2];
    const float* Wb   = (const float*)d_in[3];
    const float* a    = (const float*)d_in[4];

    const int n  = in_sizes[0] / D_IN;    // 100000
    const int ne = in_sizes[1] / 2;       // 1600000

    const int* e0a = edge;
    const int* e1a = edge + ne;
    float* out = (float*)d_out;

    char* wsp = (char*)d_ws;
    unsigned* data16 = (unsigned*)wsp; wsp += (size_t)n * 32 * sizeof(unsigned);
    float* s       = (float*)wsp;  wsp += (size_t)n * sizeof(float);
    float* t       = (float*)wsp;  wsp += (size_t)n * sizeof(float);
    int*   cursor2 = (int*)wsp;    wsp += 2048 * sizeof(int);
    float* wT      = (float*)wsp;  wsp += (size_t)D_IN * D_OUT * sizeof(float);
    unsigned int* region2 = (unsigned int*)wsp; wsp += (size_t)NSB * CAP2 * sizeof(unsigned int);

    hipMemsetAsync(cursor2, 0, 2048 * sizeof(int), stream);

    wprep_kernel<<<(D_IN * D_OUT + 255) / 256, 256, 0, stream>>>(Ww, wT);

    proj_kernel<<<(n + 63) / 64, 256, 0, stream>>>(
        h, wT, Wb, a, data16, s, t, n);

    bin1_kernel<<<(ne + CHUNK1 - 1) / CHUNK1, 1024, 0, stream>>>(
        e0a, e1a, cursor2, region2, ne);

    agg_kernel<<<NSB, 512, 0, stream>>>(
        cursor2, region2, s, t, (const __half2*)data16, out, n);
}

// Round 14
// 121.265 us; speedup vs baseline: 1.6890x; 1.0342x over previous
//
#include <hip/hip_runtime.h>
#include <hip/hip_bf16.h>
#include <hip/hip_fp16.h>

#define D_IN   128
#define D_OUT  64

#define SB_NODES  128      // nodes per bucket
#define NSB       784      // ceil(100000/128)
#define CAP2      2432     // region slots (mean ~2046, +8.5 sigma)
#define CHUNK1    2048     // edges per bin1 block (1024 thr x 2)

static __device__ __forceinline__ unsigned pack_h2(float a, float b) {
    __half2 h = __floats2half2_rn(a, b);
    return *reinterpret_cast<unsigned*>(&h);
}

// ---------------------------------------------------------------------------
// W prep: wT[k][c] = W[c][k]
// ---------------------------------------------------------------------------
__global__ __launch_bounds__(256) void wprep_kernel(
    const float* __restrict__ Ww, float* __restrict__ wT)
{
    const int i = blockIdx.x * 256 + threadIdx.x;
    if (i < D_IN * D_OUT) {
        const int k = i >> 6;
        const int c = i & 63;
        wT[i] = Ww[c * D_IN + k];
    }
}

// ---------------------------------------------------------------------------
// Projection: block = 64 rows x 4 waves; h tile staged ONCE in LDS (padded),
// wave q computes output quarter [q*16,q*16+16) for all 64 rows (lane=row).
// Weight addresses wave-uniform -> scalar pipe.
// ---------------------------------------------------------------------------
__global__ __launch_bounds__(256) void proj_kernel(
    const float* __restrict__ h, const float* __restrict__ wT,
    const float* __restrict__ Wb, const float* __restrict__ a,
    unsigned* __restrict__ data16, float* __restrict__ s_out, float* __restrict__ t_out,
    int n)
{
    __shared__ float hs[64][129];      // +1 pad: read bank = (lane+k)%32, free
    __shared__ float psum_s[4][64];
    __shared__ float psum_t[4][64];

    const int tid  = threadIdx.x;
    const int lane = tid & 63;
    const int wv   = tid >> 6;
    const int q    = __builtin_amdgcn_readfirstlane(wv);
    const int r0   = blockIdx.x * 64;

    // cooperative stage: 64 rows x 32 float4 (coalesced global reads)
    for (int i = tid; i < 64 * 32; i += 256) {
        const int row = i >> 5;
        const int kq  = i & 31;
        float4 v = make_float4(0.f, 0.f, 0.f, 0.f);
        if (r0 + row < n)
            v = ((const float4*)h)[(size_t)(r0 + row) * 32 + kq];
        hs[row][4*kq+0] = v.x;
        hs[row][4*kq+1] = v.y;
        hs[row][4*kq+2] = v.z;
        hs[row][4*kq+3] = v.w;
    }
    __syncthreads();

    const int row  = r0 + lane;
    const bool live = (row < n);

    float acc[16];
    #pragma unroll
    for (int c = 0; c < 16; ++c) acc[c] = Wb[q * 16 + c];

    #pragma unroll 1
    for (int k = 0; k < D_IN; k += 4) {
        const float h0 = hs[lane][k + 0];
        const float h1 = hs[lane][k + 1];
        const float h2 = hs[lane][k + 2];
        const float h3 = hs[lane][k + 3];
        const float* __restrict__ w0 = wT + (size_t)(k + 0) * D_OUT + q * 16;
        const float* __restrict__ w1 = wT + (size_t)(k + 1) * D_OUT + q * 16;
        const float* __restrict__ w2 = wT + (size_t)(k + 2) * D_OUT + q * 16;
        const float* __restrict__ w3 = wT + (size_t)(k + 3) * D_OUT + q * 16;
        #pragma unroll
        for (int c = 0; c < 16; ++c)
            acc[c] = fmaf(h3, w3[c],
                     fmaf(h2, w2[c],
                     fmaf(h1, w1[c],
                     fmaf(h0, w0[c], acc[c]))));
    }

    // partial s/t over this quarter
    float sp = 0.f, tp = 0.f;
    #pragma unroll
    for (int c = 0; c < 16; ++c) {
        sp = fmaf(acc[c], a[q * 16 + c], sp);
        tp = fmaf(acc[c], a[D_OUT + q * 16 + c], tp);
    }
    psum_s[wv][lane] = sp;
    psum_t[wv][lane] = tp;

    if (live) {
        uint4 pk0, pk1;
        pk0.x = pack_h2(acc[0],  acc[1]);
        pk0.y = pack_h2(acc[2],  acc[3]);
        pk0.z = pack_h2(acc[4],  acc[5]);
        pk0.w = pack_h2(acc[6],  acc[7]);
        pk1.x = pack_h2(acc[8],  acc[9]);
        pk1.y = pack_h2(acc[10], acc[11]);
        pk1.z = pack_h2(acc[12], acc[13]);
        pk1.w = pack_h2(acc[14], acc[15]);
        uint4* __restrict__ dq = (uint4*)(data16 + (size_t)row * 32 + q * 8);
        dq[0] = pk0;
        dq[1] = pk1;
    }

    __syncthreads();
    if (wv == 0 && live) {
        const float ss = psum_s[0][lane] + psum_s[1][lane] + psum_s[2][lane] + psum_s[3][lane];
        const float ts = psum_t[0][lane] + psum_t[1][lane] + psum_t[2][lane] + psum_t[3][lane];
        s_out[row] = ss;
        t_out[row] = ts;
    }
}

// ---------------------------------------------------------------------------
// bin1: edges -> 784 regions. Record = (u&127)<<17 | e1.
// ---------------------------------------------------------------------------
__global__ __launch_bounds__(1024) void bin1_kernel(
    const int* __restrict__ e0a, const int* __restrict__ e1a,
    int* __restrict__ cursor2, unsigned int* __restrict__ region2, int ne)
{
    __shared__ int cnt[NSB];
    __shared__ int basev[NSB];

    const int tid  = threadIdx.x;
    const int base = blockIdx.x * CHUNK1;

    if (tid < NSB) cnt[tid] = 0;
    __syncthreads();

    int bj[2]; unsigned rc[2];
    #pragma unroll
    for (int j = 0; j < 2; ++j) {
        const int i = base + j * 1024 + tid;
        if (i < ne) {
            const int u = e0a[i];
            const int v = e1a[i];
            bj[j] = u >> 7;
            rc[j] = ((unsigned)(u & (SB_NODES - 1)) << 17) | (unsigned)v;
            atomicAdd(&cnt[bj[j]], 1);
        } else bj[j] = -1;
    }
    __syncthreads();

    if (tid < NSB) {
        const int c = cnt[tid];
        basev[tid] = (c > 0) ? atomicAdd(&cursor2[tid], c) : 0;
        cnt[tid] = 0;
    }
    __syncthreads();

    #pragma unroll
    for (int j = 0; j < 2; ++j) {
        if (bj[j] >= 0) {
            const int p = basev[bj[j]] + atomicAdd(&cnt[bj[j]], 1);
            if (p < CAP2) region2[(size_t)bj[j] * CAP2 + p] = rc[j];
        }
    }
}

// ---------------------------------------------------------------------------
// agg: one 512-thread block per 128-node bucket (784 blocks, no tail).
// Stage region + weights in LDS, per-node LDS scatter, 8 waves x 16 nodes.
// ---------------------------------------------------------------------------
__global__ __launch_bounds__(512) void agg_kernel(
    const int* __restrict__ cursor2, const unsigned int* __restrict__ region2,
    const float* __restrict__ s, const float* __restrict__ t,
    const __half2* __restrict__ data16, float* __restrict__ out, int n)
{
    __shared__ unsigned       rrec[CAP2];
    __shared__ unsigned short rwh[CAP2];
    __shared__ int            sv[CAP2];
    __shared__ unsigned short sw[CAP2];
    __shared__ int   lcnt[SB_NODES];
    __shared__ int   loff[SB_NODES];
    __shared__ float wacc[SB_NODES];
    __shared__ float s_lds[SB_NODES];
    __shared__ int   wtot;

    const int sb  = blockIdx.x;
    const int tid = threadIdx.x;
    const int u0  = sb << 7;
    if (u0 >= n) return;                       // uniform per block

    const int cnt2 = min(cursor2[sb], CAP2);
    const unsigned int* __restrict__ reg = region2 + (size_t)sb * CAP2;

    if (tid < SB_NODES) {
        lcnt[tid] = 0;
        wacc[tid] = 0.f;
        const int u = u0 + tid;
        s_lds[tid] = (u < n) ? s[u] : 0.f;
    }
    __syncthreads();

    // pass 1: stage + weight + histogram
    for (int i = tid; i < cnt2; i += 512) {
        const unsigned r = reg[i];
        rrec[i] = r;
        const int ul = (int)(r >> 17);
        const int v  = (int)(r & 0x1FFFFu);
        const float raw = s_lds[ul] + t[v];
        const float lr  = raw > 0.f ? raw : 0.2f * raw;
        const __half wh = __float2half(__expf(lr * 0.125f));
        rwh[i] = __half_as_ushort(wh);
        atomicAdd(&lcnt[ul], 1);
        atomicAdd(&wacc[ul], __half2float(wh));
    }
    __syncthreads();

    // 2-wave exclusive scan of lcnt[128]
    if (tid < SB_NODES) {
        const int d = lcnt[tid];
        int x = d;
        #pragma unroll
        for (int off = 1; off < 64; off <<= 1) {
            int y = __shfl_up(x, off);
            if ((tid & 63) >= off) x += y;
        }
        loff[tid] = x - d;
        if (tid == 63) wtot = x;
        lcnt[tid] = 0;
    }
    __syncthreads();
    if (tid >= 64 && tid < SB_NODES) loff[tid] += wtot;
    __syncthreads();

    // pass 2: LDS-internal scatter into per-node lists
    for (int i = tid; i < cnt2; i += 512) {
        const unsigned r = rrec[i];
        const int ul = (int)(r >> 17);
        const int p  = loff[ul] + atomicAdd(&lcnt[ul], 1);
        sv[p] = (int)(r & 0x1FFFFu);
        sw[p] = rwh[i];
    }
    __syncthreads();

    // pass 3: 8 waves x 16 nodes gather-accumulate
    const int lane = tid & 63;
    const int wv   = tid >> 6;
    const int half = lane >> 5;
    const int c2   = lane & 31;

    for (int ul = wv * 16; ul < wv * 16 + 16; ++ul) {
        const int u = u0 + ul;
        if (u >= n) break;
        const int start = loff[ul];
        const int deg   = lcnt[ul];

        float ax = 0.f, ay = 0.f;
        int j = 0;
        for (; j + 16 <= deg; j += 16) {
            const int e = start + j + half;
            const int v0 = sv[e +  0], v1 = sv[e +  2], v2 = sv[e +  4], v3 = sv[e +  6];
            const int v4 = sv[e +  8], v5 = sv[e + 10], v6 = sv[e + 12], v7 = sv[e + 14];
            const float w0 = __half2float(__ushort_as_half(sw[e +  0]));
            const float w1 = __half2float(__ushort_as_half(sw[e +  2]));
            const float w2 = __half2float(__ushort_as_half(sw[e +  4]));
            const float w3 = __half2float(__ushort_as_half(sw[e +  6]));
            const float w4 = __half2float(__ushort_as_half(sw[e +  8]));
            const float w5 = __half2float(__ushort_as_half(sw[e + 10]));
            const float w6 = __half2float(__ushort_as_half(sw[e + 12]));
            const float w7 = __half2float(__ushort_as_half(sw[e + 14]));
            const float2 f0 = __half22float2(data16[(size_t)v0 * 32 + c2]);
            const float2 f1 = __half22float2(data16[(size_t)v1 * 32 + c2]);
            const float2 f2 = __half22float2(data16[(size_t)v2 * 32 + c2]);
            const float2 f3 = __half22float2(data16[(size_t)v3 * 32 + c2]);
            const float2 f4 = __half22float2(data16[(size_t)v4 * 32 + c2]);
            const float2 f5 = __half22float2(data16[(size_t)v5 * 32 + c2]);
            const float2 f6 = __half22float2(data16[(size_t)v6 * 32 + c2]);
            const float2 f7 = __half22float2(data16[(size_t)v7 * 32 + c2]);
            ax = fmaf(w0, f0.x, ax); ay = fmaf(w0, f0.y, ay);
            ax = fmaf(w1, f1.x, ax); ay = fmaf(w1, f1.y, ay);
            ax = fmaf(w2, f2.x, ax); ay = fmaf(w2, f2.y, ay);
            ax = fmaf(w3, f3.x, ax); ay = fmaf(w3, f3.y, ay);
            ax = fmaf(w4, f4.x, ax); ay = fmaf(w4, f4.y, ay);
            ax = fmaf(w5, f5.x, ax); ay = fmaf(w5, f5.y, ay);
            ax = fmaf(w6, f6.x, ax); ay = fmaf(w6, f6.y, ay);
            ax = fmaf(w7, f7.x, ax); ay = fmaf(w7, f7.y, ay);
        }
        for (; j + 8 <= deg; j += 8) {
            const int e = start + j + half;
            const int v0 = sv[e + 0], v1 = sv[e + 2], v2 = sv[e + 4], v3 = sv[e + 6];
            const float w0 = __half2float(__ushort_as_half(sw[e + 0]));
            const float w1 = __half2float(__ushort_as_half(sw[e + 2]));
            const float w2 = __half2float(__ushort_as_half(sw[e + 4]));
            const float w3 = __half2float(__ushort_as_half(sw[e + 6]));
            const float2 f0 = __half22float2(data16[(size_t)v0 * 32 + c2]);
            const float2 f1 = __half22float2(data16[(size_t)v1 * 32 + c2]);
            const float2 f2 = __half22float2(data16[(size_t)v2 * 32 + c2]);
            const float2 f3 = __half22float2(data16[(size_t)v3 * 32 + c2]);
            ax = fmaf(w0, f0.x, ax); ay = fmaf(w0, f0.y, ay);
            ax = fmaf(w1, f1.x, ax); ay = fmaf(w1, f1.y, ay);
            ax = fmaf(w2, f2.x, ax); ay = fmaf(w2, f2.y, ay);
            ax = fmaf(w3, f3.x, ax); ay = fmaf(w3, f3.y, ay);
        }
        for (; j < deg; j += 2) {
            if (j + half < deg) {
                const int e = start + j + half;
                const int v = sv[e];
                const float w = __half2float(__ushort_as_half(sw[e]));
                const float2 f = __half22float2(data16[(size_t)v * 32 + c2]);
                ax = fmaf(w, f.x, ax); ay = fmaf(w, f.y, ay);
            }
        }

        ax += __shfl_xor(ax, 32);
        ay += __shfl_xor(ay, 32);

        if (half == 0) {
            float2 o;
            if (deg == 0) {
                o = __half22float2(data16[(size_t)u * 32 + c2]);
            } else {
                const float wi = 1.0f / wacc[ul];
                o = make_float2(ax * wi, ay * wi);
            }
            ((float2*)out)[(size_t)u * 32 + c2] = o;
        }
    }
}

extern "C" void kernel_launch(void* const* d_in, const int* in_sizes, int n_in,
                              void* d_out, int out_size, void* d_ws, size_t ws_size,
                              hipStream_t stream)
{
    const float* h    = (const float*)d_in[0];
    const int*   edge = (const int*)d_in[1];
    const float* Ww   = (const float*)d_in[2];
    const float* Wb   = (const float*)d_in[3];
    const float* a    = (const float*)d_in[4];

    const int n  = in_sizes[0] / D_IN;    // 100000
    const int ne = in_sizes[1] / 2;       // 1600000

    const int* e0a = edge;
    const int* e1a = edge + ne;
    float* out = (float*)d_out;

    char* wsp = (char*)d_ws;
    unsigned* data16 = (unsigned*)wsp; wsp += (size_t)n * 32 * sizeof(unsigned);
    float* s       = (float*)wsp;  wsp += (size_t)n * sizeof(float);
    float* t       = (float*)wsp;  wsp += (size_t)n * sizeof(float);
    int*   cursor2 = (int*)wsp;    wsp += 1024 * sizeof(int);
    float* wT      = (float*)wsp;  wsp += (size_t)D_IN * D_OUT * sizeof(float);
    unsigned int* region2 = (unsigned int*)wsp; wsp += (size_t)NSB * CAP2 * sizeof(unsigned int);

    hipMemsetAsync(cursor2, 0, 1024 * sizeof(int), stream);

    wprep_kernel<<<(D_IN * D_OUT + 255) / 256, 256, 0, stream>>>(Ww, wT);

    proj_kernel<<<(n + 63) / 64, 256, 0, stream>>>(
        h, wT, Wb, a, data16, s, t, n);

    bin1_kernel<<<(ne + CHUNK1 - 1) / CHUNK1, 1024, 0, stream>>>(
        e0a, e1a, cursor2, region2, ne);

    agg_kernel<<<NSB, 512, 0, stream>>>(
        cursor2, region2, s, t, (const __half2*)data16, out, n);
}